// Round 2
// baseline (926.179 us; speedup 1.0000x reference)
//
#include <hip/hip_runtime.h>
#include <hip/hip_bf16.h>

// Problem constants
#define NB 2
#define NI 384
#define NE 64
#define NH 8
#define ND 8
#define NNI (NI*NI)                 // 147456
#define MCOLS (NI*ND)               // 3072
#define PLANE ((size_t)NI*MCOLS)    // 1179648 elems per (b,h) plane
#define NBH (NB*NH)                 // 16

struct alignas(4)  US2 { unsigned short x, y; };
struct alignas(8)  US4 { unsigned short x, y, z, w; };

__device__ __forceinline__ float bfl(unsigned u){ return __uint_as_float(u << 16); }
__device__ __forceinline__ float bfh(unsigned u){ return __uint_as_float(u & 0xffff0000u); }
__device__ __forceinline__ float bf2f(unsigned short u){ return __uint_as_float(((unsigned)u) << 16); }
__device__ __forceinline__ unsigned short f2bf(float f){
    unsigned x = __float_as_uint(f);
    x += 0x7fffu + ((x >> 16) & 1u);          // round-to-nearest-even
    return (unsigned short)(x >> 16);
}

__device__ __forceinline__ float wave_sum(float v){
    #pragma unroll
    for (int m = 32; m > 0; m >>= 1) v += __shfl_xor(v, m, 64);
    return v;
}
__device__ __forceinline__ float wave_max(float v){
    #pragma unroll
    for (int m = 32; m > 0; m >>= 1) v = fmaxf(v, __shfl_xor(v, m, 64));
    return v;
}

// ---------------------------------------------------------------------------
// Kernel A: LayerNorm + V/EG projections, scattered into GEMM-friendly layouts
//   block = (c-tile of 64) x r x b ; 256 threads
//   Vin [bh][r][c*8+dd] = V[..., dd*8+h]        (bf16)
//   Vout[bh][r][c*8+dd] = V[..., 64+dd*8+h]     (bf16)
//   Sin/Gin [bh][i=r][k=c] ; Sout/Gout [bh][k=r][i=c]   (f32)
// ---------------------------------------------------------------------------
__global__ __launch_bounds__(256) void k_a(
    const float* __restrict__ e,
    const float* __restrict__ lns, const float* __restrict__ lnb,
    const float* __restrict__ Wv,  const float* __restrict__ bV,
    const float* __restrict__ Weg, const float* __restrict__ bEG,
    unsigned short* __restrict__ Vin, unsigned short* __restrict__ Vout,
    float* __restrict__ Sin, float* __restrict__ Gin,
    float* __restrict__ Sout, float* __restrict__ Gout)
{
    __shared__ float els[64*65];     // e_ln tile, stride 65 (2-way bank alias = free)
    __shared__ float wv[64*128];
    __shared__ float weg[64*32];
    __shared__ float sc[64], bs[64], bv_s[128], beg_s[32];

    const int tid = threadIdx.x;
    const int ct = blockIdx.x, r = blockIdx.y, b = blockIdx.z;
    const int c0 = ct * 64;
    const size_t ebase = (((size_t)b * NI + r) * NI + c0) * NE;

    for (int idx = tid; idx < 4096; idx += 256){
        int cc = idx >> 6, t = idx & 63;
        els[cc*65 + t] = e[ebase + idx];
    }
    for (int idx = tid; idx < 8192; idx += 256) wv[idx] = Wv[idx];
    for (int idx = tid; idx < 2048; idx += 256) weg[idx] = Weg[idx];
    if (tid < 64){ sc[tid] = lns[tid]; bs[tid] = lnb[tid]; }
    if (tid < 128) bv_s[tid] = bV[tid];
    if (tid < 32)  beg_s[tid] = bEG[tid];
    __syncthreads();

    const int w = tid >> 6, lane = tid & 63;
    // LayerNorm, wave w owns rows [w*16, w*16+16)
    for (int s = 0; s < 16; ++s){
        int cc = w*16 + s;
        float x  = els[cc*65 + lane];
        float sm = wave_sum(x);
        float sq = wave_sum(x*x);
        float mu  = sm * (1.f/64.f);
        float var = sq * (1.f/64.f) - mu*mu;
        float y = (x - mu) * rsqrtf(var + 1e-5f) * sc[lane] + bs[lane];
        els[cc*65 + lane] = y;
    }
    __syncthreads();

    // V projection: thread owns positions pos = 2*tid, 2*tid+1 (same cc)
    const int cc = tid >> 2;
    const int d0 = (tid & 3) * 2;
    for (int p = 0; p < 16; ++p){
        int io = p >> 3, h = p & 7;
        int c1 = io*64 + d0*8 + h;
        int c2 = c1 + 8;
        float a0 = bv_s[c1], a1 = bv_s[c2];
        #pragma unroll 8
        for (int t = 0; t < 64; ++t){
            float x = els[cc*65 + t];
            a0 = fmaf(x, wv[t*128 + c1], a0);
            a1 = fmaf(x, wv[t*128 + c2], a1);
        }
        unsigned short* dst = io ? Vout : Vin;
        size_t off = (size_t)(b*NH + h) * PLANE + (size_t)r * MCOLS + (size_t)c0*8 + 2*tid;
        US2 v; v.x = f2bf(a0); v.y = f2bf(a1);
        *(US2*)&dst[off] = v;
    }

    // EG projection: wave w owns cols q = w*8 .. w*8+7 ; lane = row cc
    for (int pg = 0; pg < 8; ++pg){
        int q = w*8 + pg;
        float a = beg_s[q];
        #pragma unroll 8
        for (int t = 0; t < 64; ++t)
            a = fmaf(els[lane*65 + t], weg[t*32 + q], a);
        float* dstp = (q < 8) ? Sin : (q < 16 ? Gin : (q < 24 ? Sout : Gout));
        int h = q & 7;
        dstp[(size_t)(b*NH + h) * NNI + (size_t)r * NI + c0 + lane] = a;
    }
}

// ---------------------------------------------------------------------------
// Kernel B: in-direction softmax over k (rows contiguous), gated, in-place
// ---------------------------------------------------------------------------
__global__ __launch_bounds__(256) void k_b(
    float* __restrict__ S, const float* __restrict__ G, const float* __restrict__ mask)
{
    const int tid = threadIdx.x, w = tid >> 6, lane = tid & 63;
    const int row = blockIdx.x * 4 + w;         // row = bh*384 + i
    const int b = row / (NH*NI);
    const int i = row % NI;
    const size_t sbase = (size_t)row * NI;
    const size_t mbase = ((size_t)b * NI + i) * NI;

    float sv[6], gv[6];
    float m = -1e30f;
    #pragma unroll
    for (int q = 0; q < 6; ++q){
        int k = lane + q*64;
        float mk = mask[mbase + k];
        sv[q] = S[sbase + k] + mk;
        gv[q] = G[sbase + k] + mk;
        m = fmaxf(m, sv[q]);
    }
    m = wave_max(m);
    float ssum = 0.f;
    #pragma unroll
    for (int q = 0; q < 6; ++q){ sv[q] = expf(sv[q] - m); ssum += sv[q]; }
    ssum = wave_sum(ssum);
    float inv = 1.f / ssum;
    #pragma unroll
    for (int q = 0; q < 6; ++q){
        float sig = 1.f / (1.f + expf(-gv[q]));
        S[sbase + lane + q*64] = sv[q] * inv * sig;
    }
}

// ---------------------------------------------------------------------------
// Kernel C: out-direction softmax over k (k-major layout [bh][k][i]), gated,
// in-place; block = (i-tile of 64, bh); wave w reduces k-range [w*96, w*96+96)
// ---------------------------------------------------------------------------
__global__ __launch_bounds__(256) void k_c(
    float* __restrict__ S, const float* __restrict__ G)
{
    const int tid = threadIdx.x, w = tid >> 6, lane = tid & 63;
    const int it = blockIdx.x, bh = blockIdx.y;
    const int i = it*64 + lane;
    const size_t base = (size_t)bh * NNI + i;
    __shared__ float red[4][64];

    float m = -1e30f;
    for (int kk = 0; kk < 96; ++kk){
        int k = w*96 + kk;
        m = fmaxf(m, S[base + (size_t)k * NI]);
    }
    red[w][lane] = m;
    __syncthreads();
    float M = fmaxf(fmaxf(red[0][lane], red[1][lane]), fmaxf(red[2][lane], red[3][lane]));
    __syncthreads();

    float s = 0.f;
    for (int kk = 0; kk < 96; ++kk){
        int k = w*96 + kk;
        s += expf(S[base + (size_t)k * NI] - M);
    }
    red[w][lane] = s;
    __syncthreads();
    float T = red[0][lane] + red[1][lane] + red[2][lane] + red[3][lane];
    float inv = 1.f / T;

    for (int kk = 0; kk < 96; ++kk){
        int k = w*96 + kk;
        size_t a = base + (size_t)k * NI;
        float ev = expf(S[a] - M) * inv;
        float g  = G[a];
        S[a] = ev / (1.f + expf(-g));
    }
}

// ---------------------------------------------------------------------------
// GEMM core: 128x128 tile, BK=16, 256 threads, 8x8 micro as 2x2 float4 blocks
// ---------------------------------------------------------------------------
__device__ __forceinline__ void fma44(float (&ac)[4][4], const float4& a, const float4& b){
    float av[4] = {a.x, a.y, a.z, a.w};
    float bv[4] = {b.x, b.y, b.z, b.w};
    #pragma unroll
    for (int i = 0; i < 4; ++i)
        #pragma unroll
        for (int j = 0; j < 4; ++j)
            ac[i][j] = fmaf(av[i], bv[j], ac[i][j]);
}

// in-direction: C[bh][i][j*8+dd] = sum_k Ain[bh][i][k] * Vin[bh][j][k*8+dd]
__global__ __launch_bounds__(256) void k_d(
    const float* __restrict__ A, const unsigned short* __restrict__ V,
    unsigned short* __restrict__ C)
{
    const int tid = threadIdx.x;
    const int mt = blockIdx.x, it = blockIdx.y, bh = blockIdx.z;
    const int i0 = it*128, m0 = mt*128, j0 = m0 >> 3;
    const float* Ab = A + (size_t)bh * NNI;
    const unsigned short* Vb = V + (size_t)bh * PLANE;
    __shared__ float At[16*132];
    __shared__ float Bt[16*132];

    float acc[2][2][4][4] = {};
    const int ty = tid >> 4, tx = tid & 15;
    const int ai = tid >> 1, ak8 = (tid & 1) * 8;     // A stage (transpose)
    const int bj = tid >> 4, bk = tid & 15;           // B stage (gather)

    for (int kb = 0; kb < 24; ++kb){
        int k0 = kb * 16;
        float4 av0 = *(const float4*)&Ab[(size_t)(i0 + ai)*NI + k0 + ak8];
        float4 av1 = *(const float4*)&Ab[(size_t)(i0 + ai)*NI + k0 + ak8 + 4];
        uint4  bu  = *(const uint4*)&Vb[(size_t)(j0 + bj)*MCOLS + (size_t)k0*8 + bk*8];
        __syncthreads();
        At[(ak8+0)*132 + ai] = av0.x; At[(ak8+1)*132 + ai] = av0.y;
        At[(ak8+2)*132 + ai] = av0.z; At[(ak8+3)*132 + ai] = av0.w;
        At[(ak8+4)*132 + ai] = av1.x; At[(ak8+5)*132 + ai] = av1.y;
        At[(ak8+6)*132 + ai] = av1.z; At[(ak8+7)*132 + ai] = av1.w;
        *(float4*)&Bt[bk*132 + bj*8]     = make_float4(bfl(bu.x), bfh(bu.x), bfl(bu.y), bfh(bu.y));
        *(float4*)&Bt[bk*132 + bj*8 + 4] = make_float4(bfl(bu.z), bfh(bu.z), bfl(bu.w), bfh(bu.w));
        __syncthreads();
        #pragma unroll
        for (int kk = 0; kk < 16; ++kk){
            const float* ar = &At[kk*132];
            const float* br = &Bt[kk*132];
            float4 a0 = *(const float4*)&ar[ty*4];
            float4 a1 = *(const float4*)&ar[64 + ty*4];
            float4 b0 = *(const float4*)&br[tx*4];
            float4 b1 = *(const float4*)&br[64 + tx*4];
            fma44(acc[0][0], a0, b0); fma44(acc[0][1], a0, b1);
            fma44(acc[1][0], a1, b0); fma44(acc[1][1], a1, b1);
        }
    }
    unsigned short* Cb = C + (size_t)bh * PLANE;
    #pragma unroll
    for (int rh = 0; rh < 2; ++rh)
        #pragma unroll
        for (int ei = 0; ei < 4; ++ei){
            int i = i0 + rh*64 + ty*4 + ei;
            #pragma unroll
            for (int ch = 0; ch < 2; ++ch){
                US4 v;
                v.x = f2bf(acc[rh][ch][ei][0]); v.y = f2bf(acc[rh][ch][ei][1]);
                v.z = f2bf(acc[rh][ch][ei][2]); v.w = f2bf(acc[rh][ch][ei][3]);
                *(US4*)&Cb[(size_t)i*MCOLS + m0 + ch*64 + tx*4] = v;
            }
        }
}

// out-direction: C[bh][i][j*8+dd] = sum_k Aout[bh][k][i] * Vout[bh][k][j*8+dd]
__global__ __launch_bounds__(256) void k_e(
    const float* __restrict__ A, const unsigned short* __restrict__ V,
    unsigned short* __restrict__ C)
{
    const int tid = threadIdx.x;
    const int mt = blockIdx.x, it = blockIdx.y, bh = blockIdx.z;
    const int i0 = it*128, m0 = mt*128;
    const float* Ab = A + (size_t)bh * NNI;
    const unsigned short* Vb = V + (size_t)bh * PLANE;
    __shared__ float At[16*132];
    __shared__ float Bt[16*132];

    float acc[2][2][4][4] = {};
    const int ty = tid >> 4, tx = tid & 15;
    const int ak = tid >> 4, ai8 = (tid & 15) * 8;    // A stage (direct, k-major)
    const int bkr = tid >> 4, bm8 = (tid & 15) * 8;   // B stage (direct rows)

    for (int kb = 0; kb < 24; ++kb){
        int k0 = kb * 16;
        float4 av0 = *(const float4*)&Ab[(size_t)(k0 + ak)*NI + i0 + ai8];
        float4 av1 = *(const float4*)&Ab[(size_t)(k0 + ak)*NI + i0 + ai8 + 4];
        uint4  bu  = *(const uint4*)&Vb[(size_t)(k0 + bkr)*MCOLS + m0 + bm8];
        __syncthreads();
        *(float4*)&At[ak*132 + ai8]     = av0;
        *(float4*)&At[ak*132 + ai8 + 4] = av1;
        *(float4*)&Bt[bkr*132 + bm8]     = make_float4(bfl(bu.x), bfh(bu.x), bfl(bu.y), bfh(bu.y));
        *(float4*)&Bt[bkr*132 + bm8 + 4] = make_float4(bfl(bu.z), bfh(bu.z), bfl(bu.w), bfh(bu.w));
        __syncthreads();
        #pragma unroll
        for (int kk = 0; kk < 16; ++kk){
            const float* ar = &At[kk*132];
            const float* br = &Bt[kk*132];
            float4 a0 = *(const float4*)&ar[ty*4];
            float4 a1 = *(const float4*)&ar[64 + ty*4];
            float4 b0 = *(const float4*)&br[tx*4];
            float4 b1 = *(const float4*)&br[64 + tx*4];
            fma44(acc[0][0], a0, b0); fma44(acc[0][1], a0, b1);
            fma44(acc[1][0], a1, b0); fma44(acc[1][1], a1, b1);
        }
    }
    unsigned short* Cb = C + (size_t)bh * PLANE;
    #pragma unroll
    for (int rh = 0; rh < 2; ++rh)
        #pragma unroll
        for (int ei = 0; ei < 4; ++ei){
            int i = i0 + rh*64 + ty*4 + ei;
            #pragma unroll
            for (int ch = 0; ch < 2; ++ch){
                US4 v;
                v.x = f2bf(acc[rh][ch][ei][0]); v.y = f2bf(acc[rh][ch][ei][1]);
                v.z = f2bf(acc[rh][ch][ei][2]); v.w = f2bf(acc[rh][ch][ei][3]);
                *(US4*)&Cb[(size_t)i*MCOLS + m0 + ch*64 + tx*4] = v;
            }
        }
}

// ---------------------------------------------------------------------------
// Kernel F: epilogue — out[b,i,j,o] = b_O[o] + sum_{dd,p} va[p][jj*8+dd]*W_O[dd*16+p][o]
// block = (j-tile of 32, i, b)
// ---------------------------------------------------------------------------
__global__ __launch_bounds__(256) void k_f(
    const unsigned short* __restrict__ Vain, const unsigned short* __restrict__ Vaout,
    const float* __restrict__ Wo, const float* __restrict__ bO,
    float* __restrict__ out)
{
    __shared__ float wo[128*64];
    __shared__ float va[16*256];
    __shared__ float bos[64];
    const int tid = threadIdx.x;
    const int jt = blockIdx.x, i = blockIdx.y, b = blockIdx.z;

    for (int idx = tid; idx < 8192; idx += 256) wo[idx] = Wo[idx];
    if (tid < 64) bos[tid] = bO[tid];
    #pragma unroll
    for (int p = 0; p < 16; ++p){
        const unsigned short* src = (p < 8) ? Vain : Vaout;
        int h = p & 7;
        va[p*256 + tid] = bf2f(src[(size_t)(b*NH + h) * PLANE + (size_t)i * MCOLS + jt*256 + tid]);
    }
    __syncthreads();

    const int o = tid & 63, jg = tid >> 6;
    float acc[8];
    #pragma unroll
    for (int q = 0; q < 8; ++q) acc[q] = bos[o];

    for (int c2 = 0; c2 < 16; ++c2){
        float w8[8];
        #pragma unroll
        for (int dd = 0; dd < 8; ++dd) w8[dd] = wo[(dd*16 + c2)*64 + o];
        #pragma unroll
        for (int q = 0; q < 8; ++q){
            const float* vr = &va[c2*256 + (jg*8 + q)*8];
            float4 v0 = *(const float4*)vr;
            float4 v1 = *(const float4*)(vr + 4);
            acc[q] = fmaf(v0.x, w8[0], acc[q]); acc[q] = fmaf(v0.y, w8[1], acc[q]);
            acc[q] = fmaf(v0.z, w8[2], acc[q]); acc[q] = fmaf(v0.w, w8[3], acc[q]);
            acc[q] = fmaf(v1.x, w8[4], acc[q]); acc[q] = fmaf(v1.y, w8[5], acc[q]);
            acc[q] = fmaf(v1.z, w8[6], acc[q]); acc[q] = fmaf(v1.w, w8[7], acc[q]);
        }
    }
    const size_t obase = (((size_t)b * NI + i) * NI + jt*32) * NE;
    #pragma unroll
    for (int q = 0; q < 8; ++q){
        int jj = jg*8 + q;
        out[obase + (size_t)jj * NE + o] = acc[q];
    }
}

// ---------------------------------------------------------------------------
extern "C" void kernel_launch(void* const* d_in, const int* in_sizes, int n_in,
                              void* d_out, int out_size, void* d_ws, size_t ws_size,
                              hipStream_t stream)
{
    const float* e    = (const float*)d_in[0];
    const float* mask = (const float*)d_in[1];
    const float* lns  = (const float*)d_in[2];
    const float* lnb  = (const float*)d_in[3];
    const float* Wv   = (const float*)d_in[4];
    const float* bV   = (const float*)d_in[5];
    const float* Weg  = (const float*)d_in[6];
    const float* bEG  = (const float*)d_in[7];
    const float* Wo   = (const float*)d_in[8];
    const float* bO   = (const float*)d_in[9];

    const size_t PL = PLANE;                 // 1,179,648
    unsigned short* Vin   = (unsigned short*)d_ws;
    unsigned short* Vout  = Vin   + (size_t)NBH * PL;
    unsigned short* Vain  = Vout  + (size_t)NBH * PL;
    unsigned short* Vaout = Vain  + (size_t)NBH * PL;
    float* Sin  = (float*)(Vaout + (size_t)NBH * PL);
    float* Gin  = Sin  + (size_t)NBH * NNI;
    float* Sout = Gin  + (size_t)NBH * NNI;
    float* Gout = Sout + (size_t)NBH * NNI;
    // total ws use: 4*37,748,736 B (bf16) + 4*9,437,184 B (f32) = 188,743,680 B

    k_a<<<dim3(6, 384, 2), 256, 0, stream>>>(e, lns, lnb, Wv, bV, Weg, bEG,
                                             Vin, Vout, Sin, Gin, Sout, Gout);
    k_b<<<dim3(1536), 256, 0, stream>>>(Sin, Gin, mask);
    k_c<<<dim3(6, 16), 256, 0, stream>>>(Sout, Gout);
    k_d<<<dim3(24, 3, 16), 256, 0, stream>>>(Sin, Vin, Vain);
    k_e<<<dim3(24, 3, 16), 256, 0, stream>>>(Sout, Vout, Vaout);
    k_f<<<dim3(12, 384, 2), 256, 0, stream>>>(Vain, Vaout, Wo, bO, (float*)d_out);
}

// Round 3
// 507.740 us; speedup vs baseline: 1.8241x; 1.8241x over previous
//
#include <hip/hip_runtime.h>
#include <hip/hip_bf16.h>

// Problem constants
#define NB 2
#define NI 384
#define NE 64
#define NH 8
#define NNI (NI*NI)                 // 147456
#define NROWS (NB*NNI)              // 294912
#define MCOLS (NI*8)                // 3072
#define PLANE ((size_t)NI*MCOLS)    // 1179648 elems per (b,h) Va plane
#define KPAD 392                    // padded K stride for bf16 planes (rows step 4 banks -> 2-way = free)
#define VPLANE_E ((size_t)MCOLS*KPAD)   // 1204224 elems per V plane
#define APLANE_E ((size_t)NI*KPAD)      // 150528 elems per A plane

typedef __attribute__((ext_vector_type(8))) short short8;
typedef __attribute__((ext_vector_type(4))) float floatx4;

__device__ __forceinline__ float bf2f(unsigned short u){ return __uint_as_float(((unsigned)u) << 16); }
__device__ __forceinline__ unsigned short f2bf(float f){
    unsigned x = __float_as_uint(f);
    x += 0x7fffu + ((x >> 16) & 1u);          // round-to-nearest-even
    return (unsigned short)(x >> 16);
}

__device__ __forceinline__ float wave_sum(float v){
    #pragma unroll
    for (int m = 32; m > 0; m >>= 1) v += __shfl_xor(v, m, 64);
    return v;
}
__device__ __forceinline__ float wave_max(float v){
    #pragma unroll
    for (int m = 32; m > 0; m >>= 1) v = fmaxf(v, __shfl_xor(v, m, 64));
    return v;
}

// ---------------------------------------------------------------------------
// k_w: one-time weight prep. Wt[n][k] = W^T bf16 (n<128: W_V col n; else W_EG
// col n-128). bco = concat(b_V, b_EG) f32.
// ---------------------------------------------------------------------------
__global__ __launch_bounds__(256) void k_w(
    const float* __restrict__ Wv, const float* __restrict__ Weg,
    const float* __restrict__ bV, const float* __restrict__ bEG,
    unsigned short* __restrict__ Wt, float* __restrict__ bco)
{
    const int t = threadIdx.x;
    for (int idx = t; idx < 10240; idx += 256){
        int n = idx >> 6, k = idx & 63;
        float v = (n < 128) ? Wv[k*128 + n] : Weg[k*32 + (n-128)];
        Wt[idx] = f2bf(v);
    }
    if (t < 160) bco[t] = (t < 128) ? bV[t] : bEG[t-128];
}

// ---------------------------------------------------------------------------
// k_proj: fused LayerNorm + [128,64]@[64,160] bf16 MFMA projection + scatter.
//   rows rg = (b,i',j') of flattened e. Outputs:
//   VinP [bh][i'*8+dd][j']  (bf16, KPAD stride)   = V_in[b,i',j',dd,h]
//   VoutP[bh][j'*8+dd][i']  (bf16, KPAD stride)   = V_out[b,i',j',dd,h]
//   Sin/Gin [bh][i'][j'] f32 ; Sout/Gout [bh][j'][i'] f32 (pre-transposed so
//   both softmaxes reduce over the contiguous axis)
// ---------------------------------------------------------------------------
__global__ __launch_bounds__(256) void k_proj(
    const float* __restrict__ e, const float* __restrict__ lns, const float* __restrict__ lnb,
    const unsigned short* __restrict__ Wt, const float* __restrict__ bco,
    unsigned short* __restrict__ VinP, unsigned short* __restrict__ VoutP,
    float* __restrict__ Sin, float* __restrict__ Gin,
    float* __restrict__ Sout, float* __restrict__ Gout)
{
    __shared__ unsigned short Alds[128*72];
    __shared__ unsigned short Wlds[160*72];
    __shared__ float bcs[160];
    const int tid = threadIdx.x;
    const int r0 = blockIdx.x * 128;

    // stage W^T into padded LDS [160][72]
    #pragma unroll
    for (int p = 0; p < 5; ++p){
        int c = p*256 + tid;              // 1280 chunks of 8 bf16
        int n = c >> 3, k8 = (c & 7) * 8;
        short8 v = *(const short8*)&Wt[c*8];
        *(short8*)&Wlds[n*72 + k8] = v;
    }
    if (tid < 160) bcs[tid] = bco[tid];

    // LayerNorm: 2 passes x 64 rows; 4 lanes per row, 16 elems/lane, in regs
    const int lq = tid & 3;
    float scv[16], bsv[16];
    #pragma unroll
    for (int j = 0; j < 4; ++j){
        float4 s4 = *(const float4*)&lns[lq*16 + j*4];
        float4 b4 = *(const float4*)&lnb[lq*16 + j*4];
        scv[j*4+0]=s4.x; scv[j*4+1]=s4.y; scv[j*4+2]=s4.z; scv[j*4+3]=s4.w;
        bsv[j*4+0]=b4.x; bsv[j*4+1]=b4.y; bsv[j*4+2]=b4.z; bsv[j*4+3]=b4.w;
    }
    #pragma unroll
    for (int p = 0; p < 2; ++p){
        int lrow = p*64 + (tid >> 2);
        size_t gbase = (size_t)(r0 + lrow) * NE + lq*16;
        float xs[16];
        #pragma unroll
        for (int j = 0; j < 4; ++j){
            float4 x4 = *(const float4*)&e[gbase + j*4];
            xs[j*4+0]=x4.x; xs[j*4+1]=x4.y; xs[j*4+2]=x4.z; xs[j*4+3]=x4.w;
        }
        float s = 0.f, sq = 0.f;
        #pragma unroll
        for (int j = 0; j < 16; ++j){ s += xs[j]; sq += xs[j]*xs[j]; }
        s  += __shfl_xor(s, 1, 64);  s  += __shfl_xor(s, 2, 64);
        sq += __shfl_xor(sq, 1, 64); sq += __shfl_xor(sq, 2, 64);
        float mu = s * (1.f/64.f);
        float var = sq * (1.f/64.f) - mu*mu;
        float rs = rsqrtf(var + 1e-5f);
        short8 o0, o1;
        #pragma unroll
        for (int j = 0; j < 8; ++j){
            o0[j] = (short)f2bf((xs[j]   - mu)*rs*scv[j]   + bsv[j]);
            o1[j] = (short)f2bf((xs[j+8] - mu)*rs*scv[j+8] + bsv[j+8]);
        }
        *(short8*)&Alds[lrow*72 + lq*16]     = o0;
        *(short8*)&Alds[lrow*72 + lq*16 + 8] = o1;
    }
    __syncthreads();

    // MFMA: wave w owns rows w*32..w*32+32 (2 frags) x 160 cols (10 frags)
    const int w = tid >> 6, l = tid & 63;
    const int lr = l & 15, lk = (l >> 4) * 8;
    floatx4 acc[2][10];
    #pragma unroll
    for (int mf = 0; mf < 2; ++mf)
        #pragma unroll
        for (int nf = 0; nf < 10; ++nf)
            acc[mf][nf] = (floatx4){0.f,0.f,0.f,0.f};

    #pragma unroll
    for (int ks = 0; ks < 2; ++ks){
        int kk = ks*32 + lk;
        short8 a0 = *(const short8*)&Alds[(w*32 +  0 + lr)*72 + kk];
        short8 a1 = *(const short8*)&Alds[(w*32 + 16 + lr)*72 + kk];
        #pragma unroll
        for (int nf = 0; nf < 10; ++nf){
            short8 b = *(const short8*)&Wlds[(nf*16 + lr)*72 + kk];
            acc[0][nf] = __builtin_amdgcn_mfma_f32_16x16x32_bf16(a0, b, acc[0][nf], 0, 0, 0);
            acc[1][nf] = __builtin_amdgcn_mfma_f32_16x16x32_bf16(a1, b, acc[1][nf], 0, 0, 0);
        }
    }

    // Scatter epilogue. C/D layout: col = lane&15, row = (lane>>4)*4 + reg
    const int rowoff = (l >> 4) * 4;
    #pragma unroll
    for (int mf = 0; mf < 2; ++mf){
        #pragma unroll
        for (int q = 0; q < 4; ++q){
            int rg = r0 + w*32 + mf*16 + rowoff + q;
            int b  = rg / NNI;
            int rr = rg - b*NNI;
            int ii = rr / NI;
            int jj = rr - ii*NI;
            #pragma unroll
            for (int nf = 0; nf < 10; ++nf){
                int cg = nf*16 + lr;
                float val = acc[mf][nf][q] + bcs[cg];
                if (cg < 128){
                    int io = cg >> 6, dd = (cg >> 3) & 7, h = cg & 7;
                    unsigned short bv = f2bf(val);
                    if (io == 0)
                        VinP [(size_t)(b*8+h)*VPLANE_E + (size_t)(ii*8+dd)*KPAD + jj] = bv;
                    else
                        VoutP[(size_t)(b*8+h)*VPLANE_E + (size_t)(jj*8+dd)*KPAD + ii] = bv;
                } else {
                    int q2 = cg - 128, sel = q2 >> 3, h = q2 & 7;
                    if (sel == 0)      Sin [(size_t)(b*8+h)*NNI + (size_t)ii*NI + jj] = val;
                    else if (sel == 1) Gin [(size_t)(b*8+h)*NNI + (size_t)ii*NI + jj] = val;
                    else if (sel == 2) Sout[(size_t)(b*8+h)*NNI + (size_t)jj*NI + ii] = val;
                    else               Gout[(size_t)(b*8+h)*NNI + (size_t)jj*NI + ii] = val;
                }
            }
        }
    }
}

// ---------------------------------------------------------------------------
// k_sm: row softmax over contiguous 384 + sigmoid gate -> bf16 A plane [392]
// R = bh*384 + row. use_mask: additive mask[b, row, k] (in-direction only).
// ---------------------------------------------------------------------------
__global__ __launch_bounds__(256) void k_sm(
    const float* __restrict__ S, const float* __restrict__ G,
    const float* __restrict__ mask, unsigned short* __restrict__ Abf, int use_mask)
{
    const int tid = threadIdx.x, w = tid >> 6, lane = tid & 63;
    const int R = blockIdx.x * 4 + w;
    const size_t sbase = (size_t)R * NI;
    const int bh = R / NI, row = R - bh*NI;

    float sv[6], gv[6];
    float m = -1e30f;
    if (use_mask){
        const int b = R / (NH*NI);
        const size_t mbase = ((size_t)b * NI + row) * NI;
        #pragma unroll
        for (int q = 0; q < 6; ++q){
            int k = lane + q*64;
            float mk = mask[mbase + k];
            sv[q] = S[sbase + k] + mk;
            gv[q] = G[sbase + k] + mk;
            m = fmaxf(m, sv[q]);
        }
    } else {
        #pragma unroll
        for (int q = 0; q < 6; ++q){
            int k = lane + q*64;
            sv[q] = S[sbase + k];
            gv[q] = G[sbase + k];
            m = fmaxf(m, sv[q]);
        }
    }
    m = wave_max(m);
    float ssum = 0.f;
    #pragma unroll
    for (int q = 0; q < 6; ++q){ sv[q] = expf(sv[q] - m); ssum += sv[q]; }
    ssum = wave_sum(ssum);
    float inv = 1.f / ssum;
    unsigned short* dst = Abf + (size_t)bh * APLANE_E + (size_t)row * KPAD;
    #pragma unroll
    for (int q = 0; q < 6; ++q){
        float sig = 1.f / (1.f + expf(-gv[q]));
        dst[lane + q*64] = f2bf(sv[q] * inv * sig);
    }
}

// ---------------------------------------------------------------------------
// k_gemm: C[384,3072] = A[384,384] @ B^T (B stored [n][k]), bf16 MFMA.
// 128x128 tile, BK=64, 256 threads (2x2 waves of 64x64), reg-staged padded LDS.
// z: dir = z>>4 (0=in, 1=out), bh = z&15.
// ---------------------------------------------------------------------------
__global__ __launch_bounds__(256) void k_gemm(
    const unsigned short* __restrict__ AinP, const unsigned short* __restrict__ AoutP,
    const unsigned short* __restrict__ VinP, const unsigned short* __restrict__ VoutP,
    unsigned short* __restrict__ VaIn, unsigned short* __restrict__ VaOut)
{
    __shared__ unsigned short Al[128*72];
    __shared__ unsigned short Bl[128*72];
    const int tid = threadIdx.x;
    const int nt = blockIdx.x, mt = blockIdx.y, z = blockIdx.z;
    const int dir = z >> 4, bh = z & 15;
    const unsigned short* Ap = (dir ? AoutP : AinP) + (size_t)bh * APLANE_E;
    const unsigned short* Bp = (dir ? VoutP : VinP) + (size_t)bh * VPLANE_E;
    unsigned short* Cp = (dir ? VaOut : VaIn) + (size_t)bh * PLANE;
    const int m0 = mt*128, n0 = nt*128;

    const int w = tid >> 6, l = tid & 63;
    const int lr = l & 15, lk = (l >> 4) * 8;
    const int wr = w >> 1, wc = w & 1;

    floatx4 acc[4][4];
    #pragma unroll
    for (int mf = 0; mf < 4; ++mf)
        #pragma unroll
        for (int nf = 0; nf < 4; ++nf)
            acc[mf][nf] = (floatx4){0.f,0.f,0.f,0.f};

    for (int kb = 0; kb < 6; ++kb){
        int k0 = kb*64;
        short8 av[4], bv[4];
        #pragma unroll
        for (int p = 0; p < 4; ++p){
            int c = p*256 + tid;
            int row = c >> 3, k8 = (c & 7)*8;
            av[p] = *(const short8*)&Ap[(size_t)(m0+row)*KPAD + k0 + k8];
            bv[p] = *(const short8*)&Bp[(size_t)(n0+row)*KPAD + k0 + k8];
        }
        __syncthreads();   // previous compute done before overwriting LDS
        #pragma unroll
        for (int p = 0; p < 4; ++p){
            int c = p*256 + tid;
            int row = c >> 3, k8 = (c & 7)*8;
            *(short8*)&Al[row*72 + k8] = av[p];
            *(short8*)&Bl[row*72 + k8] = bv[p];
        }
        __syncthreads();
        #pragma unroll
        for (int ks = 0; ks < 2; ++ks){
            int kk = ks*32 + lk;
            short8 a[4], b[4];
            #pragma unroll
            for (int mf = 0; mf < 4; ++mf)
                a[mf] = *(const short8*)&Al[(wr*64 + mf*16 + lr)*72 + kk];
            #pragma unroll
            for (int nf = 0; nf < 4; ++nf)
                b[nf] = *(const short8*)&Bl[(wc*64 + nf*16 + lr)*72 + kk];
            #pragma unroll
            for (int mf = 0; mf < 4; ++mf)
                #pragma unroll
                for (int nf = 0; nf < 4; ++nf)
                    acc[mf][nf] = __builtin_amdgcn_mfma_f32_16x16x32_bf16(a[mf], b[nf], acc[mf][nf], 0, 0, 0);
        }
    }

    const int rowoff = (l >> 4) * 4;
    #pragma unroll
    for (int mf = 0; mf < 4; ++mf)
        #pragma unroll
        for (int q = 0; q < 4; ++q){
            int i = m0 + wr*64 + mf*16 + rowoff + q;
            #pragma unroll
            for (int nf = 0; nf < 4; ++nf){
                int n = n0 + wc*64 + nf*16 + lr;
                Cp[(size_t)i*MCOLS + n] = f2bf(acc[mf][nf][q]);
            }
        }
}

// ---------------------------------------------------------------------------
// k_f: epilogue — out[b,i,j,o] = b_O[o] + sum_{dd,p} va[p][jj*8+dd]*W_O[dd*16+p][o]
// (unchanged from validated round-2 kernel)
// ---------------------------------------------------------------------------
__global__ __launch_bounds__(256) void k_f(
    const unsigned short* __restrict__ Vain, const unsigned short* __restrict__ Vaout,
    const float* __restrict__ Wo, const float* __restrict__ bO,
    float* __restrict__ out)
{
    __shared__ float wo[128*64];
    __shared__ float va[16*256];
    __shared__ float bos[64];
    const int tid = threadIdx.x;
    const int jt = blockIdx.x, i = blockIdx.y, b = blockIdx.z;

    for (int idx = tid; idx < 8192; idx += 256) wo[idx] = Wo[idx];
    if (tid < 64) bos[tid] = bO[tid];
    #pragma unroll
    for (int p = 0; p < 16; ++p){
        const unsigned short* src = (p < 8) ? Vain : Vaout;
        int h = p & 7;
        va[p*256 + tid] = bf2f(src[(size_t)(b*NH + h) * PLANE + (size_t)i * MCOLS + jt*256 + tid]);
    }
    __syncthreads();

    const int o = tid & 63, jg = tid >> 6;
    float acc[8];
    #pragma unroll
    for (int q = 0; q < 8; ++q) acc[q] = bos[o];

    for (int c2 = 0; c2 < 16; ++c2){
        float w8[8];
        #pragma unroll
        for (int dd = 0; dd < 8; ++dd) w8[dd] = wo[(dd*16 + c2)*64 + o];
        #pragma unroll
        for (int q = 0; q < 8; ++q){
            const float* vr = &va[c2*256 + (jg*8 + q)*8];
            float4 v0 = *(const float4*)vr;
            float4 v1 = *(const float4*)(vr + 4);
            acc[q] = fmaf(v0.x, w8[0], acc[q]); acc[q] = fmaf(v0.y, w8[1], acc[q]);
            acc[q] = fmaf(v0.z, w8[2], acc[q]); acc[q] = fmaf(v0.w, w8[3], acc[q]);
            acc[q] = fmaf(v1.x, w8[4], acc[q]); acc[q] = fmaf(v1.y, w8[5], acc[q]);
            acc[q] = fmaf(v1.z, w8[6], acc[q]); acc[q] = fmaf(v1.w, w8[7], acc[q]);
        }
    }
    const size_t obase = (((size_t)b * NI + i) * NI + jt*32) * NE;
    #pragma unroll
    for (int q = 0; q < 8; ++q){
        int jj = jg*8 + q;
        out[obase + (size_t)jj * NE + o] = acc[q];
    }
}

// ---------------------------------------------------------------------------
extern "C" void kernel_launch(void* const* d_in, const int* in_sizes, int n_in,
                              void* d_out, int out_size, void* d_ws, size_t ws_size,
                              hipStream_t stream)
{
    const float* e    = (const float*)d_in[0];
    const float* mask = (const float*)d_in[1];
    const float* lns  = (const float*)d_in[2];
    const float* lnb  = (const float*)d_in[3];
    const float* Wv   = (const float*)d_in[4];
    const float* bV   = (const float*)d_in[5];
    const float* Weg  = (const float*)d_in[6];
    const float* bEG  = (const float*)d_in[7];
    const float* Wo   = (const float*)d_in[8];
    const float* bO   = (const float*)d_in[9];

    // ws layout (bytes):
    //   VinP  16*VPLANE_E bf16 = 38,535,168
    //   VoutP 16*VPLANE_E bf16 = 38,535,168          (ends  77,070,336)
    //   AinP  16*APLANE_E bf16 =  4,816,896          (ends  81,887,232)
    //   AoutP 16*APLANE_E bf16 =  4,816,896          (ends  86,704,128)
    //   Wt    10240 bf16 + bco 160 f32               (ends  86,725,248)
    //   Sin/Gin/Sout/Gout 4*9,437,184 f32            (ends 124,473,984)
    //   VaIn  aliases S/G region (dead by k_gemm)    (ends 124,473,984)
    //   VaOut 37,748,736                             (ends 162,222,720) < 188,743,680
    unsigned short* VinP  = (unsigned short*)d_ws;
    unsigned short* VoutP = VinP  + (size_t)16 * VPLANE_E;
    unsigned short* AinP  = VoutP + (size_t)16 * VPLANE_E;
    unsigned short* AoutP = AinP  + (size_t)16 * APLANE_E;
    unsigned short* Wt    = AoutP + (size_t)16 * APLANE_E;
    float* bco  = (float*)(Wt + 10240);
    float* Sin  = bco + 160;
    float* Gin  = Sin  + (size_t)16 * NNI;
    float* Sout = Gin  + (size_t)16 * NNI;
    float* Gout = Sout + (size_t)16 * NNI;
    unsigned short* VaIn  = (unsigned short*)Sin;           // alias: S/G dead by k_gemm
    unsigned short* VaOut = (unsigned short*)(Gout + (size_t)16 * NNI);

    k_w   <<<1, 256, 0, stream>>>(Wv, Weg, bV, bEG, Wt, bco);
    k_proj<<<NROWS/128, 256, 0, stream>>>(e, lns, lnb, Wt, bco,
                                          VinP, VoutP, Sin, Gin, Sout, Gout);
    k_sm  <<<(16*NI)/4, 256, 0, stream>>>(Sin,  Gin,  mask, AinP,  1);
    k_sm  <<<(16*NI)/4, 256, 0, stream>>>(Sout, Gout, mask, AoutP, 0);
    k_gemm<<<dim3(MCOLS/128, NI/128, 32), 256, 0, stream>>>(AinP, AoutP, VinP, VoutP, VaIn, VaOut);
    k_f   <<<dim3(12, NI, NB), 256, 0, stream>>>(VaIn, VaOut, Wo, bO, (float*)d_out);
}

// Round 4
// 258.764 us; speedup vs baseline: 3.5792x; 1.9622x over previous
//
#include <hip/hip_runtime.h>
#include <hip/hip_bf16.h>

// Problem constants
#define NB 2
#define NI 384
#define NE 64
#define NH 8
#define NNI (NI*NI)                 // 147456
#define NROWS (NB*NNI)              // 294912
#define MCOLS (NI*8)                // 3072
#define PLANE ((size_t)NI*MCOLS)    // 1179648 elems per (b,h) Va plane
#define KPAD 392                    // padded K stride for bf16 planes
#define VPLANE_E ((size_t)MCOLS*KPAD)   // 1204224 elems per V plane
#define APLANE_E ((size_t)NI*KPAD)      // 150528 elems per A plane

typedef __attribute__((ext_vector_type(8))) short short8;
typedef __attribute__((ext_vector_type(4))) float floatx4;

struct alignas(8) US4 { unsigned short x, y, z, w; };

__device__ __forceinline__ float bf2f(unsigned short u){ return __uint_as_float(((unsigned)u) << 16); }
__device__ __forceinline__ unsigned short f2bf(float f){
    unsigned x = __float_as_uint(f);
    x += 0x7fffu + ((x >> 16) & 1u);          // round-to-nearest-even
    return (unsigned short)(x >> 16);
}

__device__ __forceinline__ float wave_sum(float v){
    #pragma unroll
    for (int m = 32; m > 0; m >>= 1) v += __shfl_xor(v, m, 64);
    return v;
}
__device__ __forceinline__ float wave_max(float v){
    #pragma unroll
    for (int m = 32; m > 0; m >>= 1) v = fmaxf(v, __shfl_xor(v, m, 64));
    return v;
}

// ---------------------------------------------------------------------------
// k_w: weight prep into two 80-col slices (bf16, [n][k] k-contiguous).
//  Slice A (pass A): n<64 -> W_V col n (V_in);   n 64..79 -> W_EG col n-64 (E_in/G_in)
//  Slice B (pass B): n<64 -> W_V col 64+n (V_out); n 64..79 -> W_EG col 16+(n-64)
// ---------------------------------------------------------------------------
__global__ __launch_bounds__(256) void k_w(
    const float* __restrict__ Wv, const float* __restrict__ Weg,
    const float* __restrict__ bV, const float* __restrict__ bEG,
    unsigned short* __restrict__ WtA, unsigned short* __restrict__ WtB,
    float* __restrict__ bcoA, float* __restrict__ bcoB)
{
    const int t = threadIdx.x;
    for (int idx = t; idx < 5120; idx += 256){
        int n = idx >> 6, k = idx & 63;
        WtA[idx] = f2bf((n < 64) ? Wv[k*128 + n]      : Weg[k*32 + (n-64)]);
        WtB[idx] = f2bf((n < 64) ? Wv[k*128 + 64 + n] : Weg[k*32 + 16 + (n-64)]);
    }
    if (t < 80){
        bcoA[t] = (t < 64) ? bV[t]      : bEG[t-64];
        bcoB[t] = (t < 64) ? bV[64 + t] : bEG[16 + t-64];
    }
}

// ---------------------------------------------------------------------------
// k_proj<PASS>: fused LayerNorm + [128,64]@[64,80] bf16 MFMA + coalesced store.
// grid = (3, 384, 2) = (x=tile, y=fixed index, z=b); 128 rows per block.
// PASS 0: y = ii, x-tile over jj  -> V_in [y*8+dd][x0+t], Sin/Gin [y][x0+t]
// PASS 1: y = jj, x-tile over ii  -> V_out[y*8+dd][x0+t], Sout/Gout [y][x0+t]
// Store-address formula is identical for both passes; only the e gather
// (row-contig vs transposed-strided) differs.
// ---------------------------------------------------------------------------
template<int PASS>
__global__ __launch_bounds__(256) void k_proj(
    const float* __restrict__ e, const float* __restrict__ lns, const float* __restrict__ lnb,
    const unsigned short* __restrict__ Wt, const float* __restrict__ bco,
    unsigned short* __restrict__ Vdst, float* __restrict__ Sdst, float* __restrict__ Gdst)
{
    __shared__ unsigned short Alds[128*72];
    __shared__ unsigned short Wlds[80*72];
    __shared__ float bcs[80];
    const int tid = threadIdx.x;
    const int x0 = blockIdx.x * 128;
    const int y  = blockIdx.y;
    const int b  = blockIdx.z;
    const int z8 = b * 8;

    // stage weight slice into padded LDS [80][72]
    for (int c = tid; c < 640; c += 256){       // 640 chunks of 8 bf16
        int n = c >> 3, k8 = (c & 7) * 8;
        short8 v = *(const short8*)&Wt[c*8];
        *(short8*)&Wlds[n*72 + k8] = v;
    }
    if (tid < 80) bcs[tid] = bco[tid];

    // LayerNorm: 2 passes x 64 rows; 4 lanes per row, 16 elems/lane, in regs
    const int lq = tid & 3;
    float scv[16], bsv[16];
    #pragma unroll
    for (int j = 0; j < 4; ++j){
        float4 s4 = *(const float4*)&lns[lq*16 + j*4];
        float4 b4 = *(const float4*)&lnb[lq*16 + j*4];
        scv[j*4+0]=s4.x; scv[j*4+1]=s4.y; scv[j*4+2]=s4.z; scv[j*4+3]=s4.w;
        bsv[j*4+0]=b4.x; bsv[j*4+1]=b4.y; bsv[j*4+2]=b4.z; bsv[j*4+3]=b4.w;
    }
    #pragma unroll
    for (int p = 0; p < 2; ++p){
        int lrow = p*64 + (tid >> 2);
        size_t gbase;
        if (PASS == 0) gbase = (((size_t)(b*NI + y)) * NI + x0 + lrow) * NE + lq*16;
        else           gbase = (((size_t)(b*NI + x0 + lrow)) * NI + y) * NE + lq*16;
        float xs[16];
        #pragma unroll
        for (int j = 0; j < 4; ++j){
            float4 x4 = *(const float4*)&e[gbase + j*4];
            xs[j*4+0]=x4.x; xs[j*4+1]=x4.y; xs[j*4+2]=x4.z; xs[j*4+3]=x4.w;
        }
        float s = 0.f, sq = 0.f;
        #pragma unroll
        for (int j = 0; j < 16; ++j){ s += xs[j]; sq += xs[j]*xs[j]; }
        s  += __shfl_xor(s, 1, 64);  s  += __shfl_xor(s, 2, 64);
        sq += __shfl_xor(sq, 1, 64); sq += __shfl_xor(sq, 2, 64);
        float mu = s * (1.f/64.f);
        float var = sq * (1.f/64.f) - mu*mu;
        float rs = rsqrtf(var + 1e-5f);
        short8 o0, o1;
        #pragma unroll
        for (int j = 0; j < 8; ++j){
            o0[j] = (short)f2bf((xs[j]   - mu)*rs*scv[j]   + bsv[j]);
            o1[j] = (short)f2bf((xs[j+8] - mu)*rs*scv[j+8] + bsv[j+8]);
        }
        *(short8*)&Alds[lrow*72 + lq*16]     = o0;
        *(short8*)&Alds[lrow*72 + lq*16 + 8] = o1;
    }
    __syncthreads();

    // MFMA: wave w owns rows w*32..w*32+31 (2 frags) x 80 cols (5 frags)
    const int w = tid >> 6, l = tid & 63;
    const int lr = l & 15, lk = (l >> 4) * 8;
    floatx4 acc[2][5];
    #pragma unroll
    for (int mf = 0; mf < 2; ++mf)
        #pragma unroll
        for (int nf = 0; nf < 5; ++nf)
            acc[mf][nf] = (floatx4){0.f,0.f,0.f,0.f};

    #pragma unroll
    for (int ks = 0; ks < 2; ++ks){
        int kk = ks*32 + lk;
        short8 a0 = *(const short8*)&Alds[(w*32 +  0 + lr)*72 + kk];
        short8 a1 = *(const short8*)&Alds[(w*32 + 16 + lr)*72 + kk];
        #pragma unroll
        for (int nf = 0; nf < 5; ++nf){
            short8 bfr = *(const short8*)&Wlds[(nf*16 + lr)*72 + kk];
            acc[0][nf] = __builtin_amdgcn_mfma_f32_16x16x32_bf16(a0, bfr, acc[0][nf], 0, 0, 0);
            acc[1][nf] = __builtin_amdgcn_mfma_f32_16x16x32_bf16(a1, bfr, acc[1][nf], 0, 0, 0);
        }
    }

    // Coalesced epilogue. C/D layout: col = lane&15, row = (lane>>4)*4 + q.
    // q=0..3 are 4 CONSECUTIVE local rows -> consecutive minor-axis positions.
    const int rowoff = (l >> 4) * 4;
    #pragma unroll
    for (int mf = 0; mf < 2; ++mf){
        const int bl = x0 + w*32 + mf*16 + rowoff;   // minor-axis base, q adds 0..3
        // V columns (ca = nf*16+lr, 0..63): dd = ca>>3, h = ca&7
        #pragma unroll
        for (int nf = 0; nf < 4; ++nf){
            int ca = nf*16 + lr;
            int dd = ca >> 3, h = ca & 7;
            float bia = bcs[ca];
            US4 v;
            v.x = f2bf(acc[mf][nf][0] + bia);
            v.y = f2bf(acc[mf][nf][1] + bia);
            v.z = f2bf(acc[mf][nf][2] + bia);
            v.w = f2bf(acc[mf][nf][3] + bia);
            *(US4*)&Vdst[(size_t)(z8 + h)*VPLANE_E + (size_t)(y*8 + dd)*KPAD + bl] = v;
        }
        // S/G columns (ca = 64+lr): lr<8 -> S, else G; h = lr&7
        {
            float bia = bcs[64 + lr];
            int h = lr & 7;
            float* dst = (lr < 8) ? Sdst : Gdst;
            float4 v4 = make_float4(acc[mf][4][0] + bia, acc[mf][4][1] + bia,
                                    acc[mf][4][2] + bia, acc[mf][4][3] + bia);
            *(float4*)&dst[(size_t)(z8 + h)*NNI + (size_t)y*NI + bl] = v4;
        }
    }
}

// ---------------------------------------------------------------------------
// k_sm: row softmax over contiguous 384 + sigmoid gate -> bf16 A plane [392]
// (unchanged from validated round-3 kernel)
// ---------------------------------------------------------------------------
__global__ __launch_bounds__(256) void k_sm(
    const float* __restrict__ S, const float* __restrict__ G,
    const float* __restrict__ mask, unsigned short* __restrict__ Abf, int use_mask)
{
    const int tid = threadIdx.x, w = tid >> 6, lane = tid & 63;
    const int R = blockIdx.x * 4 + w;
    const size_t sbase = (size_t)R * NI;
    const int bh = R / NI, row = R - bh*NI;

    float sv[6], gv[6];
    float m = -1e30f;
    if (use_mask){
        const int b = R / (NH*NI);
        const size_t mbase = ((size_t)b * NI + row) * NI;
        #pragma unroll
        for (int q = 0; q < 6; ++q){
            int k = lane + q*64;
            float mk = mask[mbase + k];
            sv[q] = S[sbase + k] + mk;
            gv[q] = G[sbase + k] + mk;
            m = fmaxf(m, sv[q]);
        }
    } else {
        #pragma unroll
        for (int q = 0; q < 6; ++q){
            int k = lane + q*64;
            sv[q] = S[sbase + k];
            gv[q] = G[sbase + k];
            m = fmaxf(m, sv[q]);
        }
    }
    m = wave_max(m);
    float ssum = 0.f;
    #pragma unroll
    for (int q = 0; q < 6; ++q){ sv[q] = expf(sv[q] - m); ssum += sv[q]; }
    ssum = wave_sum(ssum);
    float inv = 1.f / ssum;
    unsigned short* dst = Abf + (size_t)bh * APLANE_E + (size_t)row * KPAD;
    #pragma unroll
    for (int q = 0; q < 6; ++q){
        float sig = 1.f / (1.f + expf(-gv[q]));
        dst[lane + q*64] = f2bf(sv[q] * inv * sig);
    }
}

// ---------------------------------------------------------------------------
// k_gemm: C[384,3072] = A[384,384] @ B^T (B stored [n][k]), bf16 MFMA.
// (unchanged from validated round-3 kernel)
// ---------------------------------------------------------------------------
__global__ __launch_bounds__(256) void k_gemm(
    const unsigned short* __restrict__ AinP, const unsigned short* __restrict__ AoutP,
    const unsigned short* __restrict__ VinP, const unsigned short* __restrict__ VoutP,
    unsigned short* __restrict__ VaIn, unsigned short* __restrict__ VaOut)
{
    __shared__ unsigned short Al[128*72];
    __shared__ unsigned short Bl[128*72];
    const int tid = threadIdx.x;
    const int nt = blockIdx.x, mt = blockIdx.y, z = blockIdx.z;
    const int dir = z >> 4, bh = z & 15;
    const unsigned short* Ap = (dir ? AoutP : AinP) + (size_t)bh * APLANE_E;
    const unsigned short* Bp = (dir ? VoutP : VinP) + (size_t)bh * VPLANE_E;
    unsigned short* Cp = (dir ? VaOut : VaIn) + (size_t)bh * PLANE;
    const int m0 = mt*128, n0 = nt*128;

    const int w = tid >> 6, l = tid & 63;
    const int lr = l & 15, lk = (l >> 4) * 8;
    const int wr = w >> 1, wc = w & 1;

    floatx4 acc[4][4];
    #pragma unroll
    for (int mf = 0; mf < 4; ++mf)
        #pragma unroll
        for (int nf = 0; nf < 4; ++nf)
            acc[mf][nf] = (floatx4){0.f,0.f,0.f,0.f};

    for (int kb = 0; kb < 6; ++kb){
        int k0 = kb*64;
        short8 av[4], bv[4];
        #pragma unroll
        for (int p = 0; p < 4; ++p){
            int c = p*256 + tid;
            int row = c >> 3, k8 = (c & 7)*8;
            av[p] = *(const short8*)&Ap[(size_t)(m0+row)*KPAD + k0 + k8];
            bv[p] = *(const short8*)&Bp[(size_t)(n0+row)*KPAD + k0 + k8];
        }
        __syncthreads();   // previous compute done before overwriting LDS
        #pragma unroll
        for (int p = 0; p < 4; ++p){
            int c = p*256 + tid;
            int row = c >> 3, k8 = (c & 7)*8;
            *(short8*)&Al[row*72 + k8] = av[p];
            *(short8*)&Bl[row*72 + k8] = bv[p];
        }
        __syncthreads();
        #pragma unroll
        for (int ks = 0; ks < 2; ++ks){
            int kk = ks*32 + lk;
            short8 a[4], b[4];
            #pragma unroll
            for (int mf = 0; mf < 4; ++mf)
                a[mf] = *(const short8*)&Al[(wr*64 + mf*16 + lr)*72 + kk];
            #pragma unroll
            for (int nf = 0; nf < 4; ++nf)
                b[nf] = *(const short8*)&Bl[(wc*64 + nf*16 + lr)*72 + kk];
            #pragma unroll
            for (int mf = 0; mf < 4; ++mf)
                #pragma unroll
                for (int nf = 0; nf < 4; ++nf)
                    acc[mf][nf] = __builtin_amdgcn_mfma_f32_16x16x32_bf16(a[mf], b[nf], acc[mf][nf], 0, 0, 0);
        }
    }

    const int rowoff = (l >> 4) * 4;
    #pragma unroll
    for (int mf = 0; mf < 4; ++mf)
        #pragma unroll
        for (int q = 0; q < 4; ++q){
            int i = m0 + wr*64 + mf*16 + rowoff + q;
            #pragma unroll
            for (int nf = 0; nf < 4; ++nf){
                int n = n0 + wc*64 + nf*16 + lr;
                Cp[(size_t)i*MCOLS + n] = f2bf(acc[mf][nf][q]);
            }
        }
}

// ---------------------------------------------------------------------------
// k_f: epilogue — out[b,i,j,o] = b_O[o] + sum_{dd,p} va[p][jj*8+dd]*W_O[dd*16+p][o]
// (unchanged from validated round-2 kernel)
// ---------------------------------------------------------------------------
__global__ __launch_bounds__(256) void k_f(
    const unsigned short* __restrict__ Vain, const unsigned short* __restrict__ Vaout,
    const float* __restrict__ Wo, const float* __restrict__ bO,
    float* __restrict__ out)
{
    __shared__ float wo[128*64];
    __shared__ float va[16*256];
    __shared__ float bos[64];
    const int tid = threadIdx.x;
    const int jt = blockIdx.x, i = blockIdx.y, b = blockIdx.z;

    for (int idx = tid; idx < 8192; idx += 256) wo[idx] = Wo[idx];
    if (tid < 64) bos[tid] = bO[tid];
    #pragma unroll
    for (int p = 0; p < 16; ++p){
        const unsigned short* src = (p < 8) ? Vain : Vaout;
        int h = p & 7;
        va[p*256 + tid] = bf2f(src[(size_t)(b*NH + h) * PLANE + (size_t)i * MCOLS + jt*256 + tid]);
    }
    __syncthreads();

    const int o = tid & 63, jg = tid >> 6;
    float acc[8];
    #pragma unroll
    for (int q = 0; q < 8; ++q) acc[q] = bos[o];

    for (int c2 = 0; c2 < 16; ++c2){
        float w8[8];
        #pragma unroll
        for (int dd = 0; dd < 8; ++dd) w8[dd] = wo[(dd*16 + c2)*64 + o];
        #pragma unroll
        for (int q = 0; q < 8; ++q){
            const float* vr = &va[c2*256 + (jg*8 + q)*8];
            float4 v0 = *(const float4*)vr;
            float4 v1 = *(const float4*)(vr + 4);
            acc[q] = fmaf(v0.x, w8[0], acc[q]); acc[q] = fmaf(v0.y, w8[1], acc[q]);
            acc[q] = fmaf(v0.z, w8[2], acc[q]); acc[q] = fmaf(v0.w, w8[3], acc[q]);
            acc[q] = fmaf(v1.x, w8[4], acc[q]); acc[q] = fmaf(v1.y, w8[5], acc[q]);
            acc[q] = fmaf(v1.z, w8[6], acc[q]); acc[q] = fmaf(v1.w, w8[7], acc[q]);
        }
    }
    const size_t obase = (((size_t)b * NI + i) * NI + jt*32) * NE;
    #pragma unroll
    for (int q = 0; q < 8; ++q){
        int jj = jg*8 + q;
        out[obase + (size_t)jj * NE + o] = acc[q];
    }
}

// ---------------------------------------------------------------------------
extern "C" void kernel_launch(void* const* d_in, const int* in_sizes, int n_in,
                              void* d_out, int out_size, void* d_ws, size_t ws_size,
                              hipStream_t stream)
{
    const float* e    = (const float*)d_in[0];
    const float* mask = (const float*)d_in[1];
    const float* lns  = (const float*)d_in[2];
    const float* lnb  = (const float*)d_in[3];
    const float* Wv   = (const float*)d_in[4];
    const float* bV   = (const float*)d_in[5];
    const float* Weg  = (const float*)d_in[6];
    const float* bEG  = (const float*)d_in[7];
    const float* Wo   = (const float*)d_in[8];
    const float* bO   = (const float*)d_in[9];

    // ws layout identical to validated round-3 (Wt region re-split into A/B slices)
    unsigned short* VinP  = (unsigned short*)d_ws;
    unsigned short* VoutP = VinP  + (size_t)16 * VPLANE_E;
    unsigned short* AinP  = VoutP + (size_t)16 * VPLANE_E;
    unsigned short* AoutP = AinP  + (size_t)16 * APLANE_E;
    unsigned short* WtA   = AoutP + (size_t)16 * APLANE_E;
    unsigned short* WtB   = WtA + 5120;
    float* bcoA = (float*)(WtB + 5120);
    float* bcoB = bcoA + 80;
    float* Sin  = bcoB + 80;
    float* Gin  = Sin  + (size_t)16 * NNI;
    float* Sout = Gin  + (size_t)16 * NNI;
    float* Gout = Sout + (size_t)16 * NNI;
    unsigned short* VaIn  = (unsigned short*)Sin;           // alias: S/G dead by k_gemm
    unsigned short* VaOut = (unsigned short*)(Gout + (size_t)16 * NNI);

    k_w<<<1, 256, 0, stream>>>(Wv, Weg, bV, bEG, WtA, WtB, bcoA, bcoB);
    k_proj<0><<<dim3(3, NI, NB), 256, 0, stream>>>(e, lns, lnb, WtA, bcoA, VinP,  Sin,  Gin);
    k_proj<1><<<dim3(3, NI, NB), 256, 0, stream>>>(e, lns, lnb, WtB, bcoB, VoutP, Sout, Gout);
    k_sm  <<<(16*NI)/4, 256, 0, stream>>>(Sin,  Gin,  mask, AinP,  1);
    k_sm  <<<(16*NI)/4, 256, 0, stream>>>(Sout, Gout, mask, AoutP, 0);
    k_gemm<<<dim3(MCOLS/128, NI/128, 32), 256, 0, stream>>>(AinP, AoutP, VinP, VoutP, VaIn, VaOut);
    k_f   <<<dim3(12, NI, NB), 256, 0, stream>>>(VaIn, VaOut, Wo, bO, (float*)d_out);
}

// Round 5
// 179.939 us; speedup vs baseline: 5.1472x; 1.4381x over previous
//
#include <hip/hip_runtime.h>
#include <hip/hip_bf16.h>

// Problem constants
#define NB 2
#define NI 384
#define NE 64
#define NH 8
#define NNI (NI*NI)                 // 147456
#define NROWS (NB*NNI)              // 294912
#define MCOLS (NI*8)                // 3072
#define PLANE ((size_t)NI*MCOLS)    // 1179648 elems per (b,h) Va plane
#define KPAD 392                    // padded K stride for bf16 planes
#define VPLANE_E ((size_t)MCOLS*KPAD)   // 1204224 elems per V plane
#define APLANE_E ((size_t)NI*KPAD)      // 150528 elems per A plane

typedef __attribute__((ext_vector_type(8))) short short8;
typedef __attribute__((ext_vector_type(4))) float floatx4;

struct alignas(8) US4 { unsigned short x, y, z, w; };

__device__ __forceinline__ float bf2f(unsigned short u){ return __uint_as_float(((unsigned)u) << 16); }
__device__ __forceinline__ unsigned short f2bf(float f){
    unsigned x = __float_as_uint(f);
    x += 0x7fffu + ((x >> 16) & 1u);          // round-to-nearest-even
    return (unsigned short)(x >> 16);
}

__device__ __forceinline__ float wave_sum(float v){
    #pragma unroll
    for (int m = 32; m > 0; m >>= 1) v += __shfl_xor(v, m, 64);
    return v;
}
__device__ __forceinline__ float wave_max(float v){
    #pragma unroll
    for (int m = 32; m > 0; m >>= 1) v = fmaxf(v, __shfl_xor(v, m, 64));
    return v;
}

// ---------------------------------------------------------------------------
// k_w: weight prep.
//  WtA/WtB: two 80-col projection slices (bf16, [n][k] k-contiguous).
//  WoT[o][c] = W_O[(c&7)*16 + (c>>3)][o]  (bf16, 64x128, c = p*8+dd order so
//  k_f2's A-fragments are contiguous short8 loads straight from Va planes).
// ---------------------------------------------------------------------------
__global__ __launch_bounds__(256) void k_w(
    const float* __restrict__ Wv, const float* __restrict__ Weg,
    const float* __restrict__ bV, const float* __restrict__ bEG,
    const float* __restrict__ Wo,
    unsigned short* __restrict__ WtA, unsigned short* __restrict__ WtB,
    float* __restrict__ bcoA, float* __restrict__ bcoB,
    unsigned short* __restrict__ WoT)
{
    const int t = threadIdx.x;
    for (int idx = t; idx < 5120; idx += 256){
        int n = idx >> 6, k = idx & 63;
        WtA[idx] = f2bf((n < 64) ? Wv[k*128 + n]      : Weg[k*32 + (n-64)]);
        WtB[idx] = f2bf((n < 64) ? Wv[k*128 + 64 + n] : Weg[k*32 + 16 + (n-64)]);
    }
    for (int idx = t; idx < 8192; idx += 256){
        int o = idx >> 7, c = idx & 127;
        int r = (c & 7)*16 + (c >> 3);
        WoT[idx] = f2bf(Wo[r*64 + o]);
    }
    if (t < 80){
        bcoA[t] = (t < 64) ? bV[t]      : bEG[t-64];
        bcoB[t] = (t < 64) ? bV[64 + t] : bEG[16 + t-64];
    }
}

// ---------------------------------------------------------------------------
// k_proj<PASS>: fused LayerNorm + [128,64]@[64,80] bf16 MFMA + coalesced store.
// (unchanged from validated round-4 kernel)
// ---------------------------------------------------------------------------
template<int PASS>
__global__ __launch_bounds__(256) void k_proj(
    const float* __restrict__ e, const float* __restrict__ lns, const float* __restrict__ lnb,
    const unsigned short* __restrict__ Wt, const float* __restrict__ bco,
    unsigned short* __restrict__ Vdst, float* __restrict__ Sdst, float* __restrict__ Gdst)
{
    __shared__ unsigned short Alds[128*72];
    __shared__ unsigned short Wlds[80*72];
    __shared__ float bcs[80];
    const int tid = threadIdx.x;
    const int x0 = blockIdx.x * 128;
    const int y  = blockIdx.y;
    const int b  = blockIdx.z;
    const int z8 = b * 8;

    for (int c = tid; c < 640; c += 256){       // 640 chunks of 8 bf16
        int n = c >> 3, k8 = (c & 7) * 8;
        short8 v = *(const short8*)&Wt[c*8];
        *(short8*)&Wlds[n*72 + k8] = v;
    }
    if (tid < 80) bcs[tid] = bco[tid];

    const int lq = tid & 3;
    float scv[16], bsv[16];
    #pragma unroll
    for (int j = 0; j < 4; ++j){
        float4 s4 = *(const float4*)&lns[lq*16 + j*4];
        float4 b4 = *(const float4*)&lnb[lq*16 + j*4];
        scv[j*4+0]=s4.x; scv[j*4+1]=s4.y; scv[j*4+2]=s4.z; scv[j*4+3]=s4.w;
        bsv[j*4+0]=b4.x; bsv[j*4+1]=b4.y; bsv[j*4+2]=b4.z; bsv[j*4+3]=b4.w;
    }
    #pragma unroll
    for (int p = 0; p < 2; ++p){
        int lrow = p*64 + (tid >> 2);
        size_t gbase;
        if (PASS == 0) gbase = (((size_t)(b*NI + y)) * NI + x0 + lrow) * NE + lq*16;
        else           gbase = (((size_t)(b*NI + x0 + lrow)) * NI + y) * NE + lq*16;
        float xs[16];
        #pragma unroll
        for (int j = 0; j < 4; ++j){
            float4 x4 = *(const float4*)&e[gbase + j*4];
            xs[j*4+0]=x4.x; xs[j*4+1]=x4.y; xs[j*4+2]=x4.z; xs[j*4+3]=x4.w;
        }
        float s = 0.f, sq = 0.f;
        #pragma unroll
        for (int j = 0; j < 16; ++j){ s += xs[j]; sq += xs[j]*xs[j]; }
        s  += __shfl_xor(s, 1, 64);  s  += __shfl_xor(s, 2, 64);
        sq += __shfl_xor(sq, 1, 64); sq += __shfl_xor(sq, 2, 64);
        float mu = s * (1.f/64.f);
        float var = sq * (1.f/64.f) - mu*mu;
        float rs = rsqrtf(var + 1e-5f);
        short8 o0, o1;
        #pragma unroll
        for (int j = 0; j < 8; ++j){
            o0[j] = (short)f2bf((xs[j]   - mu)*rs*scv[j]   + bsv[j]);
            o1[j] = (short)f2bf((xs[j+8] - mu)*rs*scv[j+8] + bsv[j+8]);
        }
        *(short8*)&Alds[lrow*72 + lq*16]     = o0;
        *(short8*)&Alds[lrow*72 + lq*16 + 8] = o1;
    }
    __syncthreads();

    const int w = tid >> 6, l = tid & 63;
    const int lr = l & 15, lk = (l >> 4) * 8;
    floatx4 acc[2][5];
    #pragma unroll
    for (int mf = 0; mf < 2; ++mf)
        #pragma unroll
        for (int nf = 0; nf < 5; ++nf)
            acc[mf][nf] = (floatx4){0.f,0.f,0.f,0.f};

    #pragma unroll
    for (int ks = 0; ks < 2; ++ks){
        int kk = ks*32 + lk;
        short8 a0 = *(const short8*)&Alds[(w*32 +  0 + lr)*72 + kk];
        short8 a1 = *(const short8*)&Alds[(w*32 + 16 + lr)*72 + kk];
        #pragma unroll
        for (int nf = 0; nf < 5; ++nf){
            short8 bfr = *(const short8*)&Wlds[(nf*16 + lr)*72 + kk];
            acc[0][nf] = __builtin_amdgcn_mfma_f32_16x16x32_bf16(a0, bfr, acc[0][nf], 0, 0, 0);
            acc[1][nf] = __builtin_amdgcn_mfma_f32_16x16x32_bf16(a1, bfr, acc[1][nf], 0, 0, 0);
        }
    }

    const int rowoff = (l >> 4) * 4;
    #pragma unroll
    for (int mf = 0; mf < 2; ++mf){
        const int bl = x0 + w*32 + mf*16 + rowoff;
        #pragma unroll
        for (int nf = 0; nf < 4; ++nf){
            int ca = nf*16 + lr;
            int dd = ca >> 3, h = ca & 7;
            float bia = bcs[ca];
            US4 v;
            v.x = f2bf(acc[mf][nf][0] + bia);
            v.y = f2bf(acc[mf][nf][1] + bia);
            v.z = f2bf(acc[mf][nf][2] + bia);
            v.w = f2bf(acc[mf][nf][3] + bia);
            *(US4*)&Vdst[(size_t)(z8 + h)*VPLANE_E + (size_t)(y*8 + dd)*KPAD + bl] = v;
        }
        {
            float bia = bcs[64 + lr];
            int h = lr & 7;
            float* dst = (lr < 8) ? Sdst : Gdst;
            float4 v4 = make_float4(acc[mf][4][0] + bia, acc[mf][4][1] + bia,
                                    acc[mf][4][2] + bia, acc[mf][4][3] + bia);
            *(float4*)&dst[(size_t)(z8 + h)*NNI + (size_t)y*NI + bl] = v4;
        }
    }
}

// ---------------------------------------------------------------------------
// k_sm: row softmax over contiguous 384 + sigmoid gate -> bf16 A plane [392]
// (unchanged from validated round-3 kernel)
// ---------------------------------------------------------------------------
__global__ __launch_bounds__(256) void k_sm(
    const float* __restrict__ S, const float* __restrict__ G,
    const float* __restrict__ mask, unsigned short* __restrict__ Abf, int use_mask)
{
    const int tid = threadIdx.x, w = tid >> 6, lane = tid & 63;
    const int R = blockIdx.x * 4 + w;
    const size_t sbase = (size_t)R * NI;
    const int bh = R / NI, row = R - bh*NI;

    float sv[6], gv[6];
    float m = -1e30f;
    if (use_mask){
        const int b = R / (NH*NI);
        const size_t mbase = ((size_t)b * NI + row) * NI;
        #pragma unroll
        for (int q = 0; q < 6; ++q){
            int k = lane + q*64;
            float mk = mask[mbase + k];
            sv[q] = S[sbase + k] + mk;
            gv[q] = G[sbase + k] + mk;
            m = fmaxf(m, sv[q]);
        }
    } else {
        #pragma unroll
        for (int q = 0; q < 6; ++q){
            int k = lane + q*64;
            sv[q] = S[sbase + k];
            gv[q] = G[sbase + k];
            m = fmaxf(m, sv[q]);
        }
    }
    m = wave_max(m);
    float ssum = 0.f;
    #pragma unroll
    for (int q = 0; q < 6; ++q){ sv[q] = expf(sv[q] - m); ssum += sv[q]; }
    ssum = wave_sum(ssum);
    float inv = 1.f / ssum;
    unsigned short* dst = Abf + (size_t)bh * APLANE_E + (size_t)row * KPAD;
    #pragma unroll
    for (int q = 0; q < 6; ++q){
        float sig = 1.f / (1.f + expf(-gv[q]));
        dst[lane + q*64] = f2bf(sv[q] * inv * sig);
    }
}

// ---------------------------------------------------------------------------
// k_gemm: C[384,3072] = A[384,384] @ B^T (B stored [n][k]), bf16 MFMA.
// (unchanged from validated round-3 kernel)
// ---------------------------------------------------------------------------
__global__ __launch_bounds__(256) void k_gemm(
    const unsigned short* __restrict__ AinP, const unsigned short* __restrict__ AoutP,
    const unsigned short* __restrict__ VinP, const unsigned short* __restrict__ VoutP,
    unsigned short* __restrict__ VaIn, unsigned short* __restrict__ VaOut)
{
    __shared__ unsigned short Al[128*72];
    __shared__ unsigned short Bl[128*72];
    const int tid = threadIdx.x;
    const int nt = blockIdx.x, mt = blockIdx.y, z = blockIdx.z;
    const int dir = z >> 4, bh = z & 15;
    const unsigned short* Ap = (dir ? AoutP : AinP) + (size_t)bh * APLANE_E;
    const unsigned short* Bp = (dir ? VoutP : VinP) + (size_t)bh * VPLANE_E;
    unsigned short* Cp = (dir ? VaOut : VaIn) + (size_t)bh * PLANE;
    const int m0 = mt*128, n0 = nt*128;

    const int w = tid >> 6, l = tid & 63;
    const int lr = l & 15, lk = (l >> 4) * 8;
    const int wr = w >> 1, wc = w & 1;

    floatx4 acc[4][4];
    #pragma unroll
    for (int mf = 0; mf < 4; ++mf)
        #pragma unroll
        for (int nf = 0; nf < 4; ++nf)
            acc[mf][nf] = (floatx4){0.f,0.f,0.f,0.f};

    for (int kb = 0; kb < 6; ++kb){
        int k0 = kb*64;
        short8 av[4], bv[4];
        #pragma unroll
        for (int p = 0; p < 4; ++p){
            int c = p*256 + tid;
            int row = c >> 3, k8 = (c & 7)*8;
            av[p] = *(const short8*)&Ap[(size_t)(m0+row)*KPAD + k0 + k8];
            bv[p] = *(const short8*)&Bp[(size_t)(n0+row)*KPAD + k0 + k8];
        }
        __syncthreads();
        #pragma unroll
        for (int p = 0; p < 4; ++p){
            int c = p*256 + tid;
            int row = c >> 3, k8 = (c & 7)*8;
            *(short8*)&Al[row*72 + k8] = av[p];
            *(short8*)&Bl[row*72 + k8] = bv[p];
        }
        __syncthreads();
        #pragma unroll
        for (int ks = 0; ks < 2; ++ks){
            int kk = ks*32 + lk;
            short8 a[4], b[4];
            #pragma unroll
            for (int mf = 0; mf < 4; ++mf)
                a[mf] = *(const short8*)&Al[(wr*64 + mf*16 + lr)*72 + kk];
            #pragma unroll
            for (int nf = 0; nf < 4; ++nf)
                b[nf] = *(const short8*)&Bl[(wc*64 + nf*16 + lr)*72 + kk];
            #pragma unroll
            for (int mf = 0; mf < 4; ++mf)
                #pragma unroll
                for (int nf = 0; nf < 4; ++nf)
                    acc[mf][nf] = __builtin_amdgcn_mfma_f32_16x16x32_bf16(a[mf], b[nf], acc[mf][nf], 0, 0, 0);
        }
    }

    const int rowoff = (l >> 4) * 4;
    #pragma unroll
    for (int mf = 0; mf < 4; ++mf)
        #pragma unroll
        for (int q = 0; q < 4; ++q){
            int i = m0 + wr*64 + mf*16 + rowoff + q;
            #pragma unroll
            for (int nf = 0; nf < 4; ++nf){
                int n = n0 + wc*64 + nf*16 + lr;
                Cp[(size_t)i*MCOLS + n] = f2bf(acc[mf][nf][q]);
            }
        }
}

// ---------------------------------------------------------------------------
// k_f2: epilogue GEMM via MFMA, no A-staging.
// out[(b,i,j), o] = bO[o] + sum_c A[(b,i,j)][c] * WoT[o][c],  c = p*8+dd,
// where A[...][c] = VaPlane_p[b-scoped][i][j*8+dd]  -> contiguous short8 per
// (lane, k-step): plane p = ks*4 + (l>>4), 16 lanes read 256B runs (coalesced).
// WoT staged in LDS padded to 136 shorts/row (lanes step 4 banks -> 2-way = free).
// block = 192 threads (3 waves x 64 j), grid (2, 384, 2) = (jt, i, b).
// ---------------------------------------------------------------------------
__global__ __launch_bounds__(192) void k_f2(
    const unsigned short* __restrict__ Vain, const unsigned short* __restrict__ Vaout,
    const unsigned short* __restrict__ WoT, const float* __restrict__ bO,
    float* __restrict__ out)
{
    __shared__ unsigned short wl[64*136];
    const int tid = threadIdx.x;
    const int jt = blockIdx.x, i = blockIdx.y, b = blockIdx.z;

    for (int cc = tid; cc < 1024; cc += 192){     // stage WoT [64][128] -> [64][136]
        int o = cc >> 4, k8 = (cc & 15) * 8;
        short8 v = *(const short8*)&WoT[cc*8];
        *(short8*)&wl[o*136 + k8] = v;
    }

    const int w = tid >> 6, l = tid & 63;
    const int lr = l & 15, lk = (l >> 4) * 8;
    const int j0 = jt*192 + w*64;

    // per-lane bias for each nf (L1-hot scalar loads)
    float bias[4];
    #pragma unroll
    for (int nf = 0; nf < 4; ++nf) bias[nf] = bO[nf*16 + lr];

    __syncthreads();

    // b-frags in registers: b[ks][nf]
    short8 bfr[4][4];
    #pragma unroll
    for (int ks = 0; ks < 4; ++ks)
        #pragma unroll
        for (int nf = 0; nf < 4; ++nf)
            bfr[ks][nf] = *(const short8*)&wl[(nf*16 + lr)*136 + ks*32 + lk];

    floatx4 acc[4][4];
    #pragma unroll
    for (int mf = 0; mf < 4; ++mf)
        #pragma unroll
        for (int nf = 0; nf < 4; ++nf)
            acc[mf][nf] = (floatx4){0.f,0.f,0.f,0.f};

    const int p_lane = (l >> 4);                  // plane sub-index from lk
    #pragma unroll
    for (int mf = 0; mf < 4; ++mf){
        int j = j0 + mf*16 + lr;
        short8 a[4];
        #pragma unroll
        for (int ks = 0; ks < 4; ++ks){
            int p = ks*4 + p_lane;                // 0..15
            const unsigned short* src = (p >= 8) ? Vaout : Vain;
            int h = p & 7;
            a[ks] = *(const short8*)&src[(size_t)(b*8 + h)*PLANE + (size_t)i*MCOLS + (size_t)j*8];
        }
        #pragma unroll
        for (int ks = 0; ks < 4; ++ks)
            #pragma unroll
            for (int nf = 0; nf < 4; ++nf)
                acc[mf][nf] = __builtin_amdgcn_mfma_f32_16x16x32_bf16(a[ks], bfr[ks][nf], acc[mf][nf], 0, 0, 0);
    }

    // store: row j = j0+mf*16+(l>>4)*4+q, col o = nf*16+lr
    const int rowoff = (l >> 4) * 4;
    const size_t obase = ((size_t)(b*NI + i)) * NI;
    #pragma unroll
    for (int mf = 0; mf < 4; ++mf)
        #pragma unroll
        for (int q = 0; q < 4; ++q){
            int j = j0 + mf*16 + rowoff + q;
            #pragma unroll
            for (int nf = 0; nf < 4; ++nf)
                out[(obase + j)*NE + nf*16 + lr] = acc[mf][nf][q] + bias[nf];
        }
}

// ---------------------------------------------------------------------------
extern "C" void kernel_launch(void* const* d_in, const int* in_sizes, int n_in,
                              void* d_out, int out_size, void* d_ws, size_t ws_size,
                              hipStream_t stream)
{
    const float* e    = (const float*)d_in[0];
    const float* mask = (const float*)d_in[1];
    const float* lns  = (const float*)d_in[2];
    const float* lnb  = (const float*)d_in[3];
    const float* Wv   = (const float*)d_in[4];
    const float* bV   = (const float*)d_in[5];
    const float* Weg  = (const float*)d_in[6];
    const float* bEG  = (const float*)d_in[7];
    const float* Wo   = (const float*)d_in[8];
    const float* bO   = (const float*)d_in[9];

    unsigned short* VinP  = (unsigned short*)d_ws;
    unsigned short* VoutP = VinP  + (size_t)16 * VPLANE_E;
    unsigned short* AinP  = VoutP + (size_t)16 * VPLANE_E;
    unsigned short* AoutP = AinP  + (size_t)16 * APLANE_E;
    unsigned short* WtA   = AoutP + (size_t)16 * APLANE_E;
    unsigned short* WtB   = WtA + 5120;
    unsigned short* WoT   = WtB + 5120;
    float* bcoA = (float*)(WoT + 8192);
    float* bcoB = bcoA + 80;
    float* Sin  = bcoB + 80;
    float* Gin  = Sin  + (size_t)16 * NNI;
    float* Sout = Gin  + (size_t)16 * NNI;
    float* Gout = Sout + (size_t)16 * NNI;
    unsigned short* VaIn  = (unsigned short*)Sin;           // alias: S/G dead by k_gemm
    unsigned short* VaOut = (unsigned short*)(Gout + (size_t)16 * NNI);

    k_w<<<1, 256, 0, stream>>>(Wv, Weg, bV, bEG, Wo, WtA, WtB, bcoA, bcoB, WoT);
    k_proj<0><<<dim3(3, NI, NB), 256, 0, stream>>>(e, lns, lnb, WtA, bcoA, VinP,  Sin,  Gin);
    k_proj<1><<<dim3(3, NI, NB), 256, 0, stream>>>(e, lns, lnb, WtB, bcoB, VoutP, Sout, Gout);
    k_sm  <<<(16*NI)/4, 256, 0, stream>>>(Sin,  Gin,  mask, AinP,  1);
    k_sm  <<<(16*NI)/4, 256, 0, stream>>>(Sout, Gout, mask, AoutP, 0);
    k_gemm<<<dim3(MCOLS/128, NI/128, 32), 256, 0, stream>>>(AinP, AoutP, VinP, VoutP, VaIn, VaOut);
    k_f2  <<<dim3(2, NI, NB), 192, 0, stream>>>(VaIn, VaOut, WoT, bO, (float*)d_out);
}

// Round 6
// 175.600 us; speedup vs baseline: 5.2744x; 1.0247x over previous
//
#include <hip/hip_runtime.h>
#include <hip/hip_bf16.h>

// Problem constants
#define NB 2
#define NI 384
#define NE 64
#define NH 8
#define NNI (NI*NI)                 // 147456
#define NROWS (NB*NNI)              // 294912
#define MCOLS (NI*8)                // 3072
#define PLANE ((size_t)NI*MCOLS)    // 1179648 elems per (b,h) Va plane
#define KPAD 392                    // padded K stride for bf16 planes
#define VPLANE_E ((size_t)MCOLS*KPAD)   // 1204224 elems per V plane
#define APLANE_E ((size_t)NI*KPAD)      // 150528 elems per A plane

typedef __attribute__((ext_vector_type(8))) short short8;
typedef __attribute__((ext_vector_type(4))) float floatx4;

struct alignas(8) US4 { unsigned short x, y, z, w; };

__device__ __forceinline__ float bf2f(unsigned short u){ return __uint_as_float(((unsigned)u) << 16); }
__device__ __forceinline__ unsigned short f2bf(float f){
    unsigned x = __float_as_uint(f);
    x += 0x7fffu + ((x >> 16) & 1u);          // round-to-nearest-even
    return (unsigned short)(x >> 16);
}

__device__ __forceinline__ float wave_sum(float v){
    #pragma unroll
    for (int m = 32; m > 0; m >>= 1) v += __shfl_xor(v, m, 64);
    return v;
}
__device__ __forceinline__ float wave_max(float v){
    #pragma unroll
    for (int m = 32; m > 0; m >>= 1) v = fmaxf(v, __shfl_xor(v, m, 64));
    return v;
}

// ---------------------------------------------------------------------------
// k_w: weight prep (unchanged from validated round-5 kernel).
// ---------------------------------------------------------------------------
__global__ __launch_bounds__(256) void k_w(
    const float* __restrict__ Wv, const float* __restrict__ Weg,
    const float* __restrict__ bV, const float* __restrict__ bEG,
    const float* __restrict__ Wo,
    unsigned short* __restrict__ WtA, unsigned short* __restrict__ WtB,
    float* __restrict__ bcoA, float* __restrict__ bcoB,
    unsigned short* __restrict__ WoT)
{
    const int t = threadIdx.x;
    for (int idx = t; idx < 5120; idx += 256){
        int n = idx >> 6, k = idx & 63;
        WtA[idx] = f2bf((n < 64) ? Wv[k*128 + n]      : Weg[k*32 + (n-64)]);
        WtB[idx] = f2bf((n < 64) ? Wv[k*128 + 64 + n] : Weg[k*32 + 16 + (n-64)]);
    }
    for (int idx = t; idx < 8192; idx += 256){
        int o = idx >> 7, c = idx & 127;
        int r = (c & 7)*16 + (c >> 3);
        WoT[idx] = f2bf(Wo[r*64 + o]);
    }
    if (t < 80){
        bcoA[t] = (t < 64) ? bV[t]      : bEG[t-64];
        bcoB[t] = (t < 64) ? bV[64 + t] : bEG[16 + t-64];
    }
}

// ---------------------------------------------------------------------------
// k_proj<PASS>: fused LayerNorm + [128,64]@[64,80] bf16 MFMA + coalesced store.
// (unchanged from validated round-4 kernel)
// ---------------------------------------------------------------------------
template<int PASS>
__global__ __launch_bounds__(256) void k_proj(
    const float* __restrict__ e, const float* __restrict__ lns, const float* __restrict__ lnb,
    const unsigned short* __restrict__ Wt, const float* __restrict__ bco,
    unsigned short* __restrict__ Vdst, float* __restrict__ Sdst, float* __restrict__ Gdst)
{
    __shared__ unsigned short Alds[128*72];
    __shared__ unsigned short Wlds[80*72];
    __shared__ float bcs[80];
    const int tid = threadIdx.x;
    const int x0 = blockIdx.x * 128;
    const int y  = blockIdx.y;
    const int b  = blockIdx.z;
    const int z8 = b * 8;

    for (int c = tid; c < 640; c += 256){       // 640 chunks of 8 bf16
        int n = c >> 3, k8 = (c & 7) * 8;
        short8 v = *(const short8*)&Wt[c*8];
        *(short8*)&Wlds[n*72 + k8] = v;
    }
    if (tid < 80) bcs[tid] = bco[tid];

    const int lq = tid & 3;
    float scv[16], bsv[16];
    #pragma unroll
    for (int j = 0; j < 4; ++j){
        float4 s4 = *(const float4*)&lns[lq*16 + j*4];
        float4 b4 = *(const float4*)&lnb[lq*16 + j*4];
        scv[j*4+0]=s4.x; scv[j*4+1]=s4.y; scv[j*4+2]=s4.z; scv[j*4+3]=s4.w;
        bsv[j*4+0]=b4.x; bsv[j*4+1]=b4.y; bsv[j*4+2]=b4.z; bsv[j*4+3]=b4.w;
    }
    #pragma unroll
    for (int p = 0; p < 2; ++p){
        int lrow = p*64 + (tid >> 2);
        size_t gbase;
        if (PASS == 0) gbase = (((size_t)(b*NI + y)) * NI + x0 + lrow) * NE + lq*16;
        else           gbase = (((size_t)(b*NI + x0 + lrow)) * NI + y) * NE + lq*16;
        float xs[16];
        #pragma unroll
        for (int j = 0; j < 4; ++j){
            float4 x4 = *(const float4*)&e[gbase + j*4];
            xs[j*4+0]=x4.x; xs[j*4+1]=x4.y; xs[j*4+2]=x4.z; xs[j*4+3]=x4.w;
        }
        float s = 0.f, sq = 0.f;
        #pragma unroll
        for (int j = 0; j < 16; ++j){ s += xs[j]; sq += xs[j]*xs[j]; }
        s  += __shfl_xor(s, 1, 64);  s  += __shfl_xor(s, 2, 64);
        sq += __shfl_xor(sq, 1, 64); sq += __shfl_xor(sq, 2, 64);
        float mu = s * (1.f/64.f);
        float var = sq * (1.f/64.f) - mu*mu;
        float rs = rsqrtf(var + 1e-5f);
        short8 o0, o1;
        #pragma unroll
        for (int j = 0; j < 8; ++j){
            o0[j] = (short)f2bf((xs[j]   - mu)*rs*scv[j]   + bsv[j]);
            o1[j] = (short)f2bf((xs[j+8] - mu)*rs*scv[j+8] + bsv[j+8]);
        }
        *(short8*)&Alds[lrow*72 + lq*16]     = o0;
        *(short8*)&Alds[lrow*72 + lq*16 + 8] = o1;
    }
    __syncthreads();

    const int w = tid >> 6, l = tid & 63;
    const int lr = l & 15, lk = (l >> 4) * 8;
    floatx4 acc[2][5];
    #pragma unroll
    for (int mf = 0; mf < 2; ++mf)
        #pragma unroll
        for (int nf = 0; nf < 5; ++nf)
            acc[mf][nf] = (floatx4){0.f,0.f,0.f,0.f};

    #pragma unroll
    for (int ks = 0; ks < 2; ++ks){
        int kk = ks*32 + lk;
        short8 a0 = *(const short8*)&Alds[(w*32 +  0 + lr)*72 + kk];
        short8 a1 = *(const short8*)&Alds[(w*32 + 16 + lr)*72 + kk];
        #pragma unroll
        for (int nf = 0; nf < 5; ++nf){
            short8 bfr = *(const short8*)&Wlds[(nf*16 + lr)*72 + kk];
            acc[0][nf] = __builtin_amdgcn_mfma_f32_16x16x32_bf16(a0, bfr, acc[0][nf], 0, 0, 0);
            acc[1][nf] = __builtin_amdgcn_mfma_f32_16x16x32_bf16(a1, bfr, acc[1][nf], 0, 0, 0);
        }
    }

    const int rowoff = (l >> 4) * 4;
    #pragma unroll
    for (int mf = 0; mf < 2; ++mf){
        const int bl = x0 + w*32 + mf*16 + rowoff;
        #pragma unroll
        for (int nf = 0; nf < 4; ++nf){
            int ca = nf*16 + lr;
            int dd = ca >> 3, h = ca & 7;
            float bia = bcs[ca];
            US4 v;
            v.x = f2bf(acc[mf][nf][0] + bia);
            v.y = f2bf(acc[mf][nf][1] + bia);
            v.z = f2bf(acc[mf][nf][2] + bia);
            v.w = f2bf(acc[mf][nf][3] + bia);
            *(US4*)&Vdst[(size_t)(z8 + h)*VPLANE_E + (size_t)(y*8 + dd)*KPAD + bl] = v;
        }
        {
            float bia = bcs[64 + lr];
            int h = lr & 7;
            float* dst = (lr < 8) ? Sdst : Gdst;
            float4 v4 = make_float4(acc[mf][4][0] + bia, acc[mf][4][1] + bia,
                                    acc[mf][4][2] + bia, acc[mf][4][3] + bia);
            *(float4*)&dst[(size_t)(z8 + h)*NNI + (size_t)y*NI + bl] = v4;
        }
    }
}

// ---------------------------------------------------------------------------
// k_sm: row softmax over contiguous 384 + sigmoid gate -> bf16 A plane [392]
// (unchanged from validated round-3 kernel)
// ---------------------------------------------------------------------------
__global__ __launch_bounds__(256) void k_sm(
    const float* __restrict__ S, const float* __restrict__ G,
    const float* __restrict__ mask, unsigned short* __restrict__ Abf, int use_mask)
{
    const int tid = threadIdx.x, w = tid >> 6, lane = tid & 63;
    const int R = blockIdx.x * 4 + w;
    const size_t sbase = (size_t)R * NI;
    const int bh = R / NI, row = R - bh*NI;

    float sv[6], gv[6];
    float m = -1e30f;
    if (use_mask){
        const int b = R / (NH*NI);
        const size_t mbase = ((size_t)b * NI + row) * NI;
        #pragma unroll
        for (int q = 0; q < 6; ++q){
            int k = lane + q*64;
            float mk = mask[mbase + k];
            sv[q] = S[sbase + k] + mk;
            gv[q] = G[sbase + k] + mk;
            m = fmaxf(m, sv[q]);
        }
    } else {
        #pragma unroll
        for (int q = 0; q < 6; ++q){
            int k = lane + q*64;
            sv[q] = S[sbase + k];
            gv[q] = G[sbase + k];
            m = fmaxf(m, sv[q]);
        }
    }
    m = wave_max(m);
    float ssum = 0.f;
    #pragma unroll
    for (int q = 0; q < 6; ++q){ sv[q] = expf(sv[q] - m); ssum += sv[q]; }
    ssum = wave_sum(ssum);
    float inv = 1.f / ssum;
    unsigned short* dst = Abf + (size_t)bh * APLANE_E + (size_t)row * KPAD;
    #pragma unroll
    for (int q = 0; q < 6; ++q){
        float sig = 1.f / (1.f + expf(-gv[q]));
        dst[lane + q*64] = f2bf(sv[q] * inv * sig);
    }
}

// ---------------------------------------------------------------------------
// k_gemm v2: C[384,3072] = A[384,384] @ B^T (B stored [n][k]), bf16 MFMA.
// Block tile 128x256, 256 threads = 2x2 waves, wave tile 64x128 (acc 4x8).
// Per-lane per K-step(64): 24 ds_read_b128 (~288 cyc) vs 64 MFMA (~320 cyc)
// -> MFMA-pipe-dominant (was 16 reads vs 32 MFMA = LDS-bound at 64x64).
// 1D grid 1152, bijective XCD swizzle (chunk 144 = 4 whole planes per XCD,
// nt-fastest so each A-tile stays L2-hot across its 12 nt-consumers).
// ---------------------------------------------------------------------------
__global__ __launch_bounds__(256, 2) void k_gemm(
    const unsigned short* __restrict__ AinP, const unsigned short* __restrict__ AoutP,
    const unsigned short* __restrict__ VinP, const unsigned short* __restrict__ VoutP,
    unsigned short* __restrict__ VaIn, unsigned short* __restrict__ VaOut)
{
    __shared__ unsigned short Al[128*72];
    __shared__ unsigned short Bl[256*72];
    const int tid = threadIdx.x;

    // XCD-aware bijective swizzle: 1152 blocks = 8 XCDs x 144
    const int L = blockIdx.x;
    const int W = (L & 7) * 144 + (L >> 3);
    const int nt = W % 12;
    const int mt = (W / 12) % 3;
    const int z  = W / 36;
    const int dir = z >> 4, bh = z & 15;
    const unsigned short* Ap = (dir ? AoutP : AinP) + (size_t)bh * APLANE_E;
    const unsigned short* Bp = (dir ? VoutP : VinP) + (size_t)bh * VPLANE_E;
    unsigned short* Cp = (dir ? VaOut : VaIn) + (size_t)bh * PLANE;
    const int m0 = mt*128, n0 = nt*256;

    const int w = tid >> 6, l = tid & 63;
    const int lr = l & 15, lk = (l >> 4) * 8;
    const int wr = w >> 1, wc = w & 1;

    floatx4 acc[4][8];
    #pragma unroll
    for (int mf = 0; mf < 4; ++mf)
        #pragma unroll
        for (int nf = 0; nf < 8; ++nf)
            acc[mf][nf] = (floatx4){0.f,0.f,0.f,0.f};

    const int srow = tid >> 3, sk8 = (tid & 7) * 8;   // staging row/col per thread
    for (int kb = 0; kb < 6; ++kb){
        int k0 = kb*64;
        short8 av[4], bv[8];
        #pragma unroll
        for (int p = 0; p < 4; ++p)
            av[p] = *(const short8*)&Ap[(size_t)(m0 + p*32 + srow)*KPAD + k0 + sk8];
        #pragma unroll
        for (int p = 0; p < 8; ++p)
            bv[p] = *(const short8*)&Bp[(size_t)(n0 + p*32 + srow)*KPAD + k0 + sk8];
        __syncthreads();   // previous compute done before overwriting LDS
        #pragma unroll
        for (int p = 0; p < 4; ++p)
            *(short8*)&Al[(p*32 + srow)*72 + sk8] = av[p];
        #pragma unroll
        for (int p = 0; p < 8; ++p)
            *(short8*)&Bl[(p*32 + srow)*72 + sk8] = bv[p];
        __syncthreads();
        #pragma unroll
        for (int ks = 0; ks < 2; ++ks){
            int kk = ks*32 + lk;
            short8 a[4], b[8];
            #pragma unroll
            for (int mf = 0; mf < 4; ++mf)
                a[mf] = *(const short8*)&Al[(wr*64 + mf*16 + lr)*72 + kk];
            #pragma unroll
            for (int nf = 0; nf < 8; ++nf)
                b[nf] = *(const short8*)&Bl[(wc*128 + nf*16 + lr)*72 + kk];
            #pragma unroll
            for (int mf = 0; mf < 4; ++mf)
                #pragma unroll
                for (int nf = 0; nf < 8; ++nf)
                    acc[mf][nf] = __builtin_amdgcn_mfma_f32_16x16x32_bf16(a[mf], b[nf], acc[mf][nf], 0, 0, 0);
        }
    }

    const int rowoff = (l >> 4) * 4;
    #pragma unroll
    for (int mf = 0; mf < 4; ++mf)
        #pragma unroll
        for (int q = 0; q < 4; ++q){
            int i = m0 + wr*64 + mf*16 + rowoff + q;
            #pragma unroll
            for (int nf = 0; nf < 8; ++nf){
                int n = n0 + wc*128 + nf*16 + lr;
                Cp[(size_t)i*MCOLS + n] = f2bf(acc[mf][nf][q]);
            }
        }
}

// ---------------------------------------------------------------------------
// k_f2: epilogue GEMM via MFMA, no A-staging.
// (unchanged from validated round-5 kernel)
// ---------------------------------------------------------------------------
__global__ __launch_bounds__(192) void k_f2(
    const unsigned short* __restrict__ Vain, const unsigned short* __restrict__ Vaout,
    const unsigned short* __restrict__ WoT, const float* __restrict__ bO,
    float* __restrict__ out)
{
    __shared__ unsigned short wl[64*136];
    const int tid = threadIdx.x;
    const int jt = blockIdx.x, i = blockIdx.y, b = blockIdx.z;

    for (int cc = tid; cc < 1024; cc += 192){     // stage WoT [64][128] -> [64][136]
        int o = cc >> 4, k8 = (cc & 15) * 8;
        short8 v = *(const short8*)&WoT[cc*8];
        *(short8*)&wl[o*136 + k8] = v;
    }

    const int w = tid >> 6, l = tid & 63;
    const int lr = l & 15, lk = (l >> 4) * 8;
    const int j0 = jt*192 + w*64;

    float bias[4];
    #pragma unroll
    for (int nf = 0; nf < 4; ++nf) bias[nf] = bO[nf*16 + lr];

    __syncthreads();

    short8 bfr[4][4];
    #pragma unroll
    for (int ks = 0; ks < 4; ++ks)
        #pragma unroll
        for (int nf = 0; nf < 4; ++nf)
            bfr[ks][nf] = *(const short8*)&wl[(nf*16 + lr)*136 + ks*32 + lk];

    floatx4 acc[4][4];
    #pragma unroll
    for (int mf = 0; mf < 4; ++mf)
        #pragma unroll
        for (int nf = 0; nf < 4; ++nf)
            acc[mf][nf] = (floatx4){0.f,0.f,0.f,0.f};

    const int p_lane = (l >> 4);
    #pragma unroll
    for (int mf = 0; mf < 4; ++mf){
        int j = j0 + mf*16 + lr;
        short8 a[4];
        #pragma unroll
        for (int ks = 0; ks < 4; ++ks){
            int p = ks*4 + p_lane;
            const unsigned short* src = (p >= 8) ? Vaout : Vain;
            int h = p & 7;
            a[ks] = *(const short8*)&src[(size_t)(b*8 + h)*PLANE + (size_t)i*MCOLS + (size_t)j*8];
        }
        #pragma unroll
        for (int ks = 0; ks < 4; ++ks)
            #pragma unroll
            for (int nf = 0; nf < 4; ++nf)
                acc[mf][nf] = __builtin_amdgcn_mfma_f32_16x16x32_bf16(a[ks], bfr[ks][nf], acc[mf][nf], 0, 0, 0);
    }

    const int rowoff = (l >> 4) * 4;
    const size_t obase = ((size_t)(b*NI + i)) * NI;
    #pragma unroll
    for (int mf = 0; mf < 4; ++mf)
        #pragma unroll
        for (int q = 0; q < 4; ++q){
            int j = j0 + mf*16 + rowoff + q;
            #pragma unroll
            for (int nf = 0; nf < 4; ++nf)
                out[(obase + j)*NE + nf*16 + lr] = acc[mf][nf][q] + bias[nf];
        }
}

// ---------------------------------------------------------------------------
extern "C" void kernel_launch(void* const* d_in, const int* in_sizes, int n_in,
                              void* d_out, int out_size, void* d_ws, size_t ws_size,
                              hipStream_t stream)
{
    const float* e    = (const float*)d_in[0];
    const float* mask = (const float*)d_in[1];
    const float* lns  = (const float*)d_in[2];
    const float* lnb  = (const float*)d_in[3];
    const float* Wv   = (const float*)d_in[4];
    const float* bV   = (const float*)d_in[5];
    const float* Weg  = (const float*)d_in[6];
    const float* bEG  = (const float*)d_in[7];
    const float* Wo   = (const float*)d_in[8];
    const float* bO   = (const float*)d_in[9];

    unsigned short* VinP  = (unsigned short*)d_ws;
    unsigned short* VoutP = VinP  + (size_t)16 * VPLANE_E;
    unsigned short* AinP  = VoutP + (size_t)16 * VPLANE_E;
    unsigned short* AoutP = AinP  + (size_t)16 * APLANE_E;
    unsigned short* WtA   = AoutP + (size_t)16 * APLANE_E;
    unsigned short* WtB   = WtA + 5120;
    unsigned short* WoT   = WtB + 5120;
    float* bcoA = (float*)(WoT + 8192);
    float* bcoB = bcoA + 80;
    float* Sin  = bcoB + 80;
    float* Gin  = Sin  + (size_t)16 * NNI;
    float* Sout = Gin  + (size_t)16 * NNI;
    float* Gout = Sout + (size_t)16 * NNI;
    unsigned short* VaIn  = (unsigned short*)Sin;           // alias: S/G dead by k_gemm
    unsigned short* VaOut = (unsigned short*)(Gout + (size_t)16 * NNI);

    k_w<<<1, 256, 0, stream>>>(Wv, Weg, bV, bEG, Wo, WtA, WtB, bcoA, bcoB, WoT);
    k_proj<0><<<dim3(3, NI, NB), 256, 0, stream>>>(e, lns, lnb, WtA, bcoA, VinP,  Sin,  Gin);
    k_proj<1><<<dim3(3, NI, NB), 256, 0, stream>>>(e, lns, lnb, WtB, bcoB, VoutP, Sout, Gout);
    k_sm  <<<(16*NI)/4, 256, 0, stream>>>(Sin,  Gin,  mask, AinP,  1);
    k_sm  <<<(16*NI)/4, 256, 0, stream>>>(Sout, Gout, mask, AoutP, 0);
    k_gemm<<<dim3(1152), 256, 0, stream>>>(AinP, AoutP, VinP, VoutP, VaIn, VaOut);
    k_f2  <<<dim3(2, NI, NB), 192, 0, stream>>>(VaIn, VaOut, WoT, bO, (float*)d_out);
}

// Round 7
// 174.567 us; speedup vs baseline: 5.3056x; 1.0059x over previous
//
#include <hip/hip_runtime.h>
#include <hip/hip_bf16.h>

// Problem constants
#define NB 2
#define NI 384
#define NE 64
#define NH 8
#define NNI (NI*NI)                 // 147456
#define NROWS (NB*NNI)              // 294912
#define MCOLS (NI*8)                // 3072
#define PLANE ((size_t)NI*MCOLS)    // 1179648 elems per (b,h) Va plane
#define KPAD 392                    // padded K stride for bf16 planes (784 B rows, 16B-aligned)
#define VPLANE_E ((size_t)MCOLS*KPAD)   // 1204224 elems per V plane
#define APLANE_E ((size_t)NI*KPAD)      // 150528 elems per A plane

typedef __attribute__((ext_vector_type(8))) short short8;
typedef __attribute__((ext_vector_type(4))) float floatx4;

struct alignas(8) US4 { unsigned short x, y, z, w; };

__device__ __forceinline__ float bf2f(unsigned short u){ return __uint_as_float(((unsigned)u) << 16); }
__device__ __forceinline__ unsigned short f2bf(float f){
    unsigned x = __float_as_uint(f);
    x += 0x7fffu + ((x >> 16) & 1u);          // round-to-nearest-even
    return (unsigned short)(x >> 16);
}

__device__ __forceinline__ float wave_sum(float v){
    #pragma unroll
    for (int m = 32; m > 0; m >>= 1) v += __shfl_xor(v, m, 64);
    return v;
}
__device__ __forceinline__ float wave_max(float v){
    #pragma unroll
    for (int m = 32; m > 0; m >>= 1) v = fmaxf(v, __shfl_xor(v, m, 64));
    return v;
}

// async global->LDS, 16B per lane; LDS dest is wave-uniform base + lane*16
__device__ __forceinline__ void gl_lds16(const unsigned short* g, unsigned short* l){
    __builtin_amdgcn_global_load_lds(
        (__attribute__((address_space(1))) void*)(g),
        (__attribute__((address_space(3))) void*)(l), 16, 0, 0);
}

// ---------------------------------------------------------------------------
// k_w: weight prep (unchanged from validated round-5 kernel).
// ---------------------------------------------------------------------------
__global__ __launch_bounds__(256) void k_w(
    const float* __restrict__ Wv, const float* __restrict__ Weg,
    const float* __restrict__ bV, const float* __restrict__ bEG,
    const float* __restrict__ Wo,
    unsigned short* __restrict__ WtA, unsigned short* __restrict__ WtB,
    float* __restrict__ bcoA, float* __restrict__ bcoB,
    unsigned short* __restrict__ WoT)
{
    const int t = threadIdx.x;
    for (int idx = t; idx < 5120; idx += 256){
        int n = idx >> 6, k = idx & 63;
        WtA[idx] = f2bf((n < 64) ? Wv[k*128 + n]      : Weg[k*32 + (n-64)]);
        WtB[idx] = f2bf((n < 64) ? Wv[k*128 + 64 + n] : Weg[k*32 + 16 + (n-64)]);
    }
    for (int idx = t; idx < 8192; idx += 256){
        int o = idx >> 7, c = idx & 127;
        int r = (c & 7)*16 + (c >> 3);
        WoT[idx] = f2bf(Wo[r*64 + o]);
    }
    if (t < 80){
        bcoA[t] = (t < 64) ? bV[t]      : bEG[t-64];
        bcoB[t] = (t < 64) ? bV[64 + t] : bEG[16 + t-64];
    }
}

// ---------------------------------------------------------------------------
// k_proj<PASS>: fused LayerNorm + [128,64]@[64,80] bf16 MFMA + coalesced store.
// (unchanged from validated round-4 kernel)
// ---------------------------------------------------------------------------
template<int PASS>
__global__ __launch_bounds__(256) void k_proj(
    const float* __restrict__ e, const float* __restrict__ lns, const float* __restrict__ lnb,
    const unsigned short* __restrict__ Wt, const float* __restrict__ bco,
    unsigned short* __restrict__ Vdst, float* __restrict__ Sdst, float* __restrict__ Gdst)
{
    __shared__ unsigned short Alds[128*72];
    __shared__ unsigned short Wlds[80*72];
    __shared__ float bcs[80];
    const int tid = threadIdx.x;
    const int x0 = blockIdx.x * 128;
    const int y  = blockIdx.y;
    const int b  = blockIdx.z;
    const int z8 = b * 8;

    for (int c = tid; c < 640; c += 256){       // 640 chunks of 8 bf16
        int n = c >> 3, k8 = (c & 7) * 8;
        short8 v = *(const short8*)&Wt[c*8];
        *(short8*)&Wlds[n*72 + k8] = v;
    }
    if (tid < 80) bcs[tid] = bco[tid];

    const int lq = tid & 3;
    float scv[16], bsv[16];
    #pragma unroll
    for (int j = 0; j < 4; ++j){
        float4 s4 = *(const float4*)&lns[lq*16 + j*4];
        float4 b4 = *(const float4*)&lnb[lq*16 + j*4];
        scv[j*4+0]=s4.x; scv[j*4+1]=s4.y; scv[j*4+2]=s4.z; scv[j*4+3]=s4.w;
        bsv[j*4+0]=b4.x; bsv[j*4+1]=b4.y; bsv[j*4+2]=b4.z; bsv[j*4+3]=b4.w;
    }
    #pragma unroll
    for (int p = 0; p < 2; ++p){
        int lrow = p*64 + (tid >> 2);
        size_t gbase;
        if (PASS == 0) gbase = (((size_t)(b*NI + y)) * NI + x0 + lrow) * NE + lq*16;
        else           gbase = (((size_t)(b*NI + x0 + lrow)) * NI + y) * NE + lq*16;
        float xs[16];
        #pragma unroll
        for (int j = 0; j < 4; ++j){
            float4 x4 = *(const float4*)&e[gbase + j*4];
            xs[j*4+0]=x4.x; xs[j*4+1]=x4.y; xs[j*4+2]=x4.z; xs[j*4+3]=x4.w;
        }
        float s = 0.f, sq = 0.f;
        #pragma unroll
        for (int j = 0; j < 16; ++j){ s += xs[j]; sq += xs[j]*xs[j]; }
        s  += __shfl_xor(s, 1, 64);  s  += __shfl_xor(s, 2, 64);
        sq += __shfl_xor(sq, 1, 64); sq += __shfl_xor(sq, 2, 64);
        float mu = s * (1.f/64.f);
        float var = sq * (1.f/64.f) - mu*mu;
        float rs = rsqrtf(var + 1e-5f);
        short8 o0, o1;
        #pragma unroll
        for (int j = 0; j < 8; ++j){
            o0[j] = (short)f2bf((xs[j]   - mu)*rs*scv[j]   + bsv[j]);
            o1[j] = (short)f2bf((xs[j+8] - mu)*rs*scv[j+8] + bsv[j+8]);
        }
        *(short8*)&Alds[lrow*72 + lq*16]     = o0;
        *(short8*)&Alds[lrow*72 + lq*16 + 8] = o1;
    }
    __syncthreads();

    const int w = tid >> 6, l = tid & 63;
    const int lr = l & 15, lk = (l >> 4) * 8;
    floatx4 acc[2][5];
    #pragma unroll
    for (int mf = 0; mf < 2; ++mf)
        #pragma unroll
        for (int nf = 0; nf < 5; ++nf)
            acc[mf][nf] = (floatx4){0.f,0.f,0.f,0.f};

    #pragma unroll
    for (int ks = 0; ks < 2; ++ks){
        int kk = ks*32 + lk;
        short8 a0 = *(const short8*)&Alds[(w*32 +  0 + lr)*72 + kk];
        short8 a1 = *(const short8*)&Alds[(w*32 + 16 + lr)*72 + kk];
        #pragma unroll
        for (int nf = 0; nf < 5; ++nf){
            short8 bfr = *(const short8*)&Wlds[(nf*16 + lr)*72 + kk];
            acc[0][nf] = __builtin_amdgcn_mfma_f32_16x16x32_bf16(a0, bfr, acc[0][nf], 0, 0, 0);
            acc[1][nf] = __builtin_amdgcn_mfma_f32_16x16x32_bf16(a1, bfr, acc[1][nf], 0, 0, 0);
        }
    }

    const int rowoff = (l >> 4) * 4;
    #pragma unroll
    for (int mf = 0; mf < 2; ++mf){
        const int bl = x0 + w*32 + mf*16 + rowoff;
        #pragma unroll
        for (int nf = 0; nf < 4; ++nf){
            int ca = nf*16 + lr;
            int dd = ca >> 3, h = ca & 7;
            float bia = bcs[ca];
            US4 v;
            v.x = f2bf(acc[mf][nf][0] + bia);
            v.y = f2bf(acc[mf][nf][1] + bia);
            v.z = f2bf(acc[mf][nf][2] + bia);
            v.w = f2bf(acc[mf][nf][3] + bia);
            *(US4*)&Vdst[(size_t)(z8 + h)*VPLANE_E + (size_t)(y*8 + dd)*KPAD + bl] = v;
        }
        {
            float bia = bcs[64 + lr];
            int h = lr & 7;
            float* dst = (lr < 8) ? Sdst : Gdst;
            float4 v4 = make_float4(acc[mf][4][0] + bia, acc[mf][4][1] + bia,
                                    acc[mf][4][2] + bia, acc[mf][4][3] + bia);
            *(float4*)&dst[(size_t)(z8 + h)*NNI + (size_t)y*NI + bl] = v4;
        }
    }
}

// ---------------------------------------------------------------------------
// k_sm: row softmax over contiguous 384 + sigmoid gate -> bf16 A plane [392]
// (unchanged from validated round-3 kernel)
// ---------------------------------------------------------------------------
__global__ __launch_bounds__(256) void k_sm(
    const float* __restrict__ S, const float* __restrict__ G,
    const float* __restrict__ mask, unsigned short* __restrict__ Abf, int use_mask)
{
    const int tid = threadIdx.x, w = tid >> 6, lane = tid & 63;
    const int R = blockIdx.x * 4 + w;
    const size_t sbase = (size_t)R * NI;
    const int bh = R / NI, row = R - bh*NI;

    float sv[6], gv[6];
    float m = -1e30f;
    if (use_mask){
        const int b = R / (NH*NI);
        const size_t mbase = ((size_t)b * NI + row) * NI;
        #pragma unroll
        for (int q = 0; q < 6; ++q){
            int k = lane + q*64;
            float mk = mask[mbase + k];
            sv[q] = S[sbase + k] + mk;
            gv[q] = G[sbase + k] + mk;
            m = fmaxf(m, sv[q]);
        }
    } else {
        #pragma unroll
        for (int q = 0; q < 6; ++q){
            int k = lane + q*64;
            sv[q] = S[sbase + k];
            gv[q] = G[sbase + k];
            m = fmaxf(m, sv[q]);
        }
    }
    m = wave_max(m);
    float ssum = 0.f;
    #pragma unroll
    for (int q = 0; q < 6; ++q){ sv[q] = expf(sv[q] - m); ssum += sv[q]; }
    ssum = wave_sum(ssum);
    float inv = 1.f / ssum;
    unsigned short* dst = Abf + (size_t)bh * APLANE_E + (size_t)row * KPAD;
    #pragma unroll
    for (int q = 0; q < 6; ++q){
        float sig = 1.f / (1.f + expf(-gv[q]));
        dst[lane + q*64] = f2bf(sv[q] * inv * sig);
    }
}

// ---------------------------------------------------------------------------
// k_gemm v3: C[384,3072] = A[384,384] @ B^T (B stored [n][k]), bf16 MFMA.
// Block tile 128x256, 256 threads = 2x2 waves, wave tile 64x128 (acc 4x8).
// Staging via global_load_lds width=16 into LINEAR LDS tiles (no ds_writes,
// no staging VGPRs). XOR chunk-swizzle done on the GLOBAL source address
// (lane reads logical chunk (l&7)^((l>>3)&7)); ds_read_b128 applies the same
// XOR -> <=2-way bank aliasing on reads (free), zero write conflicts.
// 1D grid 1152, bijective XCD swizzle (chunk 144 = 4 whole planes per XCD).
// ---------------------------------------------------------------------------
__global__ __launch_bounds__(256, 2) void k_gemm(
    const unsigned short* __restrict__ AinP, const unsigned short* __restrict__ AoutP,
    const unsigned short* __restrict__ VinP, const unsigned short* __restrict__ VoutP,
    unsigned short* __restrict__ VaIn, unsigned short* __restrict__ VaOut)
{
    __shared__ unsigned short Al[128*64];    // 16 KB, linear [row][64], swizzled chunks
    __shared__ unsigned short Bl[256*64];    // 32 KB
    const int tid = threadIdx.x;

    // XCD-aware bijective swizzle: 1152 blocks = 8 XCDs x 144
    const int L = blockIdx.x;
    const int W = (L & 7) * 144 + (L >> 3);
    const int nt = W % 12;
    const int mt = (W / 12) % 3;
    const int z  = W / 36;
    const int dir = z >> 4, bh = z & 15;
    const unsigned short* Ap = (dir ? AoutP : AinP) + (size_t)bh * APLANE_E;
    const unsigned short* Bp = (dir ? VoutP : VinP) + (size_t)bh * VPLANE_E;
    unsigned short* Cp = (dir ? VaOut : VaIn) + (size_t)bh * PLANE;
    const int m0 = mt*128, n0 = nt*256;

    const int w = tid >> 6, l = tid & 63;
    const int lr = l & 15, lk4 = l >> 4;
    const int wr = w >> 1, wc = w & 1;

    // staging lane geometry: lane l covers (row_in_inst = l>>3, physical chunk = l&7)
    const int srow8  = l >> 3;                      // 0..7
    const int schunk = (l & 7) ^ (srow8 & 7);       // logical chunk to fetch

    floatx4 acc[4][8];
    #pragma unroll
    for (int mf = 0; mf < 4; ++mf)
        #pragma unroll
        for (int nf = 0; nf < 8; ++nf)
            acc[mf][nf] = (floatx4){0.f,0.f,0.f,0.f};

    for (int kb = 0; kb < 6; ++kb){
        const int k0 = kb*64;
        __syncthreads();                            // prev compute done before overwrite
        // A-tile: 16 insts of 8 rows; wave w owns insts [4w, 4w+4)
        #pragma unroll
        for (int t = 0; t < 4; ++t){
            int inst = w*4 + t;
            gl_lds16(&Ap[(size_t)(m0 + inst*8 + srow8)*KPAD + k0 + schunk*8],
                     &Al[inst*512]);
        }
        // B-tile: 32 insts; wave w owns insts [8w, 8w+8)
        #pragma unroll
        for (int t = 0; t < 8; ++t){
            int inst = w*8 + t;
            gl_lds16(&Bp[(size_t)(n0 + inst*8 + srow8)*KPAD + k0 + schunk*8],
                     &Bl[inst*512]);
        }
        asm volatile("s_waitcnt vmcnt(0)" ::: "memory");
        __syncthreads();
        #pragma unroll
        for (int ks = 0; ks < 2; ++ks){
            const int cx = ((ks*4 + lk4) ^ (lr & 7)) * 8;   // swizzled chunk offset (shorts)
            short8 a[4], b[8];
            #pragma unroll
            for (int mf = 0; mf < 4; ++mf)
                a[mf] = *(const short8*)&Al[(wr*64 + mf*16 + lr)*64 + cx];
            #pragma unroll
            for (int nf = 0; nf < 8; ++nf)
                b[nf] = *(const short8*)&Bl[(wc*128 + nf*16 + lr)*64 + cx];
            #pragma unroll
            for (int mf = 0; mf < 4; ++mf)
                #pragma unroll
                for (int nf = 0; nf < 8; ++nf)
                    acc[mf][nf] = __builtin_amdgcn_mfma_f32_16x16x32_bf16(a[mf], b[nf], acc[mf][nf], 0, 0, 0);
        }
    }

    const int rowoff = lk4 * 4;
    #pragma unroll
    for (int mf = 0; mf < 4; ++mf)
        #pragma unroll
        for (int q = 0; q < 4; ++q){
            int i = m0 + wr*64 + mf*16 + rowoff + q;
            #pragma unroll
            for (int nf = 0; nf < 8; ++nf){
                int n = n0 + wc*128 + nf*16 + lr;
                Cp[(size_t)i*MCOLS + n] = f2bf(acc[mf][nf][q]);
            }
        }
}

// ---------------------------------------------------------------------------
// k_f2: epilogue GEMM via MFMA, no A-staging.
// (unchanged from validated round-5 kernel)
// ---------------------------------------------------------------------------
__global__ __launch_bounds__(192) void k_f2(
    const unsigned short* __restrict__ Vain, const unsigned short* __restrict__ Vaout,
    const unsigned short* __restrict__ WoT, const float* __restrict__ bO,
    float* __restrict__ out)
{
    __shared__ unsigned short wl[64*136];
    const int tid = threadIdx.x;
    const int jt = blockIdx.x, i = blockIdx.y, b = blockIdx.z;

    for (int cc = tid; cc < 1024; cc += 192){     // stage WoT [64][128] -> [64][136]
        int o = cc >> 4, k8 = (cc & 15) * 8;
        short8 v = *(const short8*)&WoT[cc*8];
        *(short8*)&wl[o*136 + k8] = v;
    }

    const int w = tid >> 6, l = tid & 63;
    const int lr = l & 15, lk = (l >> 4) * 8;
    const int j0 = jt*192 + w*64;

    float bias[4];
    #pragma unroll
    for (int nf = 0; nf < 4; ++nf) bias[nf] = bO[nf*16 + lr];

    __syncthreads();

    short8 bfr[4][4];
    #pragma unroll
    for (int ks = 0; ks < 4; ++ks)
        #pragma unroll
        for (int nf = 0; nf < 4; ++nf)
            bfr[ks][nf] = *(const short8*)&wl[(nf*16 + lr)*136 + ks*32 + lk];

    floatx4 acc[4][4];
    #pragma unroll
    for (int mf = 0; mf < 4; ++mf)
        #pragma unroll
        for (int nf = 0; nf < 4; ++nf)
            acc[mf][nf] = (floatx4){0.f,0.f,0.f,0.f};

    const int p_lane = (l >> 4);
    #pragma unroll
    for (int mf = 0; mf < 4; ++mf){
        int j = j0 + mf*16 + lr;
        short8 a[4];
        #pragma unroll
        for (int ks = 0; ks < 4; ++ks){
            int p = ks*4 + p_lane;
            const unsigned short* src = (p >= 8) ? Vaout : Vain;
            int h = p & 7;
            a[ks] = *(const short8*)&src[(size_t)(b*8 + h)*PLANE + (size_t)i*MCOLS + (size_t)j*8];
        }
        #pragma unroll
        for (int ks = 0; ks < 4; ++ks)
            #pragma unroll
            for (int nf = 0; nf < 4; ++nf)
                acc[mf][nf] = __builtin_amdgcn_mfma_f32_16x16x32_bf16(a[ks], bfr[ks][nf], acc[mf][nf], 0, 0, 0);
    }

    const int rowoff = (l >> 4) * 4;
    const size_t obase = ((size_t)(b*NI + i)) * NI;
    #pragma unroll
    for (int mf = 0; mf < 4; ++mf)
        #pragma unroll
        for (int q = 0; q < 4; ++q){
            int j = j0 + mf*16 + rowoff + q;
            #pragma unroll
            for (int nf = 0; nf < 4; ++nf)
                out[(obase + j)*NE + nf*16 + lr] = acc[mf][nf][q] + bias[nf];
        }
}

// ---------------------------------------------------------------------------
extern "C" void kernel_launch(void* const* d_in, const int* in_sizes, int n_in,
                              void* d_out, int out_size, void* d_ws, size_t ws_size,
                              hipStream_t stream)
{
    const float* e    = (const float*)d_in[0];
    const float* mask = (const float*)d_in[1];
    const float* lns  = (const float*)d_in[2];
    const float* lnb  = (const float*)d_in[3];
    const float* Wv   = (const float*)d_in[4];
    const float* bV   = (const float*)d_in[5];
    const float* Weg  = (const float*)d_in[6];
    const float* bEG  = (const float*)d_in[7];
    const float* Wo   = (const float*)d_in[8];
    const float* bO   = (const float*)d_in[9];

    unsigned short* VinP  = (unsigned short*)d_ws;
    unsigned short* VoutP = VinP  + (size_t)16 * VPLANE_E;
    unsigned short* AinP  = VoutP + (size_t)16 * VPLANE_E;
    unsigned short* AoutP = AinP  + (size_t)16 * APLANE_E;
    unsigned short* WtA   = AoutP + (size_t)16 * APLANE_E;
    unsigned short* WtB   = WtA + 5120;
    unsigned short* WoT   = WtB + 5120;
    float* bcoA = (float*)(WoT + 8192);
    float* bcoB = bcoA + 80;
    float* Sin  = bcoB + 80;
    float* Gin  = Sin  + (size_t)16 * NNI;
    float* Sout = Gin  + (size_t)16 * NNI;
    float* Gout = Sout + (size_t)16 * NNI;
    unsigned short* VaIn  = (unsigned short*)Sin;           // alias: S/G dead by k_gemm
    unsigned short* VaOut = (unsigned short*)(Gout + (size_t)16 * NNI);

    k_w<<<1, 256, 0, stream>>>(Wv, Weg, bV, bEG, Wo, WtA, WtB, bcoA, bcoB, WoT);
    k_proj<0><<<dim3(3, NI, NB), 256, 0, stream>>>(e, lns, lnb, WtA, bcoA, VinP,  Sin,  Gin);
    k_proj<1><<<dim3(3, NI, NB), 256, 0, stream>>>(e, lns, lnb, WtB, bcoB, VoutP, Sout, Gout);
    k_sm  <<<(16*NI)/4, 256, 0, stream>>>(Sin,  Gin,  mask, AinP,  1);
    k_sm  <<<(16*NI)/4, 256, 0, stream>>>(Sout, Gout, mask, AoutP, 0);
    k_gemm<<<dim3(1152), 256, 0, stream>>>(AinP, AoutP, VinP, VoutP, VaIn, VaOut);
    k_f2  <<<dim3(2, NI, NB), 192, 0, stream>>>(VaIn, VaOut, WoT, bO, (float*)d_out);
}